// Round 8
// baseline (113.957 us; speedup 1.0000x reference)
//
#include <hip/hip_runtime.h>
#include <math.h>

#define Bv 2
#define Dv 192
#define Hv 192
#define Wv 192
#define Nv (Dv*Hv*Wv)          // 7,077,888 voxels per batch
#define NOUT (Bv*Nv)           // 14,155,776 warped elements

#define STAGE_CAP 8192         // 32 KB source-bbox stage (floats)

// Block tile: 16(x) x 8(y) x 4(z) = 512 threads, one output each.
// Phase 1: stage the tile's source bbox into LDS once (each source line
//   fetched once per block -> ~0.5 line-visits/output vs 2.25 direct).
// Phase 2: gather taps from LDS (zero-filled OOB = boundary masking free).
// Phase 3: LDS transpose -> fully-coalesced 64B-line stores (R7).

__device__ __forceinline__ void mm3(const float a[3][3], const float b[3][3], float c[3][3]) {
#pragma unroll
    for (int i = 0; i < 3; ++i)
#pragma unroll
        for (int j = 0; j < 3; ++j)
            c[i][j] = a[i][0]*b[0][j] + a[i][1]*b[1][j] + a[i][2]*b[2][j];
}

__global__ void compose_mats_kernel(const float* __restrict__ affine,
                                    const float* __restrict__ scale,
                                    const float* __restrict__ translate,
                                    const float* __restrict__ shear,
                                    float* __restrict__ mats_out) {
    int b = threadIdx.x;
    if (b >= Bv) return;

    float ax = affine[b*3+0], ay = affine[b*3+1], az = affine[b*3+2];
    float cx = cosf(ax), sx = sinf(ax);
    float cy = cosf(ay), sy = sinf(ay);
    float cz = cosf(az), sz = sinf(az);

    // _mk_mat transposes the written rows -> these are the transposed matrices.
    float rx[3][3] = {{1.f,0.f,0.f},{0.f,cx,sx},{0.f,-sx,cx}};
    float ry[3][3] = {{cy,0.f,-sy},{0.f,1.f,0.f},{sy,0.f,cy}};
    float rz[3][3] = {{cz,sz,0.f},{-sz,cz,0.f},{0.f,0.f,1.f}};

    float t0 = tanf(shear[b*6+0]), t1 = tanf(shear[b*6+1]), t2 = tanf(shear[b*6+2]);
    float t3 = tanf(shear[b*6+3]), t4 = tanf(shear[b*6+4]), t5 = tanf(shear[b*6+5]);
    float sh[3][3] = {{1.f,t2,t4},{t0,1.f,t5},{t1,t3,1.f}};

    float s0 = scale[b*3+0], s1 = scale[b*3+1], s2 = scale[b*3+2];

    float m1[3][3], m2[3][3], m3s[3][3], mat3[3][3];
    mm3(ry, rx, m1);
    mm3(rz, m1, m2);
#pragma unroll
    for (int j = 0; j < 3; ++j) { m3s[0][j] = s0*m2[0][j]; m3s[1][j] = s1*m2[1][j]; m3s[2][j] = s2*m2[2][j]; }
    mm3(sh, m3s, mat3);

    float tr0 = translate[b*3+0], tr1 = translate[b*3+1], tr2 = translate[b*3+2];

    float a00 = mat3[0][0], a01 = mat3[0][1], a02 = mat3[0][2];
    float a10 = mat3[1][0], a11 = mat3[1][1], a12 = mat3[1][2];
    float a20 = mat3[2][0], a21 = mat3[2][1], a22 = mat3[2][2];
    float c00 =  (a11*a22 - a12*a21);
    float c01 = -(a10*a22 - a12*a20);
    float c02 =  (a10*a21 - a11*a20);
    float det = a00*c00 + a01*c01 + a02*c02;
    float rdet = 1.0f / det;
    float inv3[3][3];
    inv3[0][0] = c00*rdet;
    inv3[0][1] = (a02*a21 - a01*a22)*rdet;
    inv3[0][2] = (a01*a12 - a02*a11)*rdet;
    inv3[1][0] = c01*rdet;
    inv3[1][1] = (a00*a22 - a02*a20)*rdet;
    inv3[1][2] = (a02*a10 - a00*a12)*rdet;
    inv3[2][0] = c02*rdet;
    inv3[2][1] = (a01*a20 - a00*a21)*rdet;
    inv3[2][2] = (a00*a11 - a01*a10)*rdet;

    float* mo = mats_out + b*12;
#pragma unroll
    for (int i = 0; i < 3; ++i) {
        mo[i*4+0] = mat3[i][0]; mo[i*4+1] = mat3[i][1]; mo[i*4+2] = mat3[i][2];
    }
    mo[0*4+3] = tr0; mo[1*4+3] = tr1; mo[2*4+3] = tr2;

    float* io = mats_out + 24 + b*12;
#pragma unroll
    for (int i = 0; i < 3; ++i) {
        io[i*4+0] = inv3[i][0]; io[i*4+1] = inv3[i][1]; io[i*4+2] = inv3[i][2];
        io[i*4+3] = -(inv3[i][0]*tr0 + inv3[i][1]*tr1 + inv3[i][2]*tr2);
    }
}

// 8-byte load from a 4-byte-aligned address (single global_load_dwordx2).
__device__ __forceinline__ float2 ld2(const float* p) {
    float2 r;
    __builtin_memcpy(&r, p, 8);
    return r;
}
__device__ __forceinline__ float4 ld4(const float* p) {
    float4 r;
    __builtin_memcpy(&r, p, 16);
    return r;
}

__global__ __launch_bounds__(512) void warp_kernel(const float* __restrict__ src,
                                                   const float* __restrict__ mats,
                                                   float* __restrict__ out) {
    __shared__ float stage[STAGE_CAP];
    __shared__ float tileO[512];

    int t    = threadIdx.x;
    int lane = t & 63;
    int wv   = t >> 6;              // 0..7
    int wvx  = wv & 3;              // waves tile 4x2x1
    int wvy  = wv >> 2;

    // gather mapping: wave = 4x4x4 cube (minimal source-row footprint)
    int lx = (lane & 3)        + (wvx << 2);   // 0..15
    int ly = ((lane >> 2) & 3) + (wvy << 2);   // 0..7
    int lz = lane >> 4;                        // 0..3

    int W0 = blockIdx.x * 16;
    int H0 = blockIdx.y * 8;
    int zt = blockIdx.z;            // 0 .. (Dv/4)*Bv - 1
    int b  = zt / (Dv/4);           // uniform
    int Z0 = (zt % (Dv/4)) * 4;

    int w = W0 + lx, h = H0 + ly, z = Z0 + lz;

    const float* M = mats + b*12;   // uniform -> scalar loads
    float m00 = M[0], m01 = M[1],  m02 = M[2],  m03 = M[3];
    float m10 = M[4], m11 = M[5],  m12 = M[6],  m13 = M[7];
    float m20 = M[8], m21 = M[9],  m22 = M[10], m23 = M[11];

    // ix = m00*(w+.5) + m01*(h+.5) + m02*(z+.5) + Cx
    float Cx = 96.0f*(m03 - m00 - m01 - m02) + 95.5f;
    float Cy = 96.0f*(m13 - m10 - m11 - m12) + 95.5f;
    float Cz = 96.0f*(m23 - m20 - m21 - m22) + 95.5f;

    float fw = w + 0.5f, fh = h + 0.5f, fzc = z + 0.5f;
    float ix = fmaf(m00, fw, fmaf(m01, fh, fmaf(m02, fzc, Cx)));
    float iy = fmaf(m10, fw, fmaf(m11, fh, fmaf(m12, fzc, Cy)));
    float iz = fmaf(m20, fw, fmaf(m21, fh, fmaf(m22, fzc, Cz)));

    float flx = floorf(ix), fly = floorf(iy), flz = floorf(iz);
    float wx = ix - flx, wy = iy - fly, wz = iz - flz;
    int x0 = (int)flx, y0 = (int)fly, z0 = (int)flz;

    const float* sb = src + (size_t)b * Nv;

    // ---- tight block-uniform source bbox (corner-exact, +-1 safety) ----
    float cxv = fmaf(m00, W0+8.0f, fmaf(m01, H0+4.0f, fmaf(m02, Z0+2.0f, Cx)));
    float cyv = fmaf(m10, W0+8.0f, fmaf(m11, H0+4.0f, fmaf(m12, Z0+2.0f, Cy)));
    float czv = fmaf(m20, W0+8.0f, fmaf(m21, H0+4.0f, fmaf(m22, Z0+2.0f, Cz)));
    float hxv = 7.5f*fabsf(m00) + 3.5f*fabsf(m01) + 1.5f*fabsf(m02);
    float hyv = 7.5f*fabsf(m10) + 3.5f*fabsf(m11) + 1.5f*fabsf(m12);
    float hzv = 7.5f*fabsf(m20) + 3.5f*fabsf(m21) + 1.5f*fabsf(m22);

    int bx0 = (int)floorf(cxv - hxv) - 1;
    int by0 = (int)floorf(cyv - hyv) - 1;
    int bz0 = (int)floorf(czv - hzv) - 1;
    int ex  = (int)floorf(cxv + hxv) + 3 - bx0;   // covers taps +1, margin +1
    int ey  = (int)floorf(cyv + hyv) + 3 - by0;
    int ez  = (int)floorf(czv + hzv) + 3 - bz0;

    int ldw   = ex | 1;             // odd row stride -> tap bank spread
    int nrows = ey * ez;
    int vol   = nrows * ldw;

    float acc = 0.0f;

    if (vol <= STAGE_CAP) {
        // ---- phase 1: stage bbox (zero-filled outside volume) ----
        int tidr = t >> 2;              // 128 row-workers
        int cb0  = (t & 3) << 2;        // 4 lanes x 4 cols = 16 cols/sweep
        for (int r = tidr; r < nrows; r += 128) {
            int dz = r / ey;            // ey uniform
            int dy = r - dz*ey;
            int gy = by0 + dy, gz = bz0 + dz;
            bool rowok = ((unsigned)gy < (unsigned)Hv) & ((unsigned)gz < (unsigned)Dv);
            int gyc = min(max(gy, 0), Hv-1);
            int gzc = min(max(gz, 0), Dv-1);
            const float* rowp = sb + (gzc*Hv + gyc)*Wv;
            int rowbase = r * ldw;
            for (int cb = cb0; cb < ex; cb += 16) {
                int gx = bx0 + cb;
                if (rowok & (gx >= 0) & (gx + 3 < Wv)) {
                    // interior fast path: one 16B load, 4 LDS writes
                    float4 v = ld4(rowp + gx);
                    stage[rowbase + cb + 0] = v.x;
                    stage[rowbase + cb + 1] = v.y;
                    stage[rowbase + cb + 2] = v.z;
                    stage[rowbase + cb + 3] = v.w;
                } else {
#pragma unroll
                    for (int k = 0; k < 4; ++k) {
                        int gxk = gx + k;
                        bool vk = rowok & ((unsigned)gxk < (unsigned)Wv);
                        int gxc = min(max(gxk, 0), Wv-1);
                        float val = rowp[gxc];
                        if (cb + k < ex) stage[rowbase + cb + k] = vk ? val : 0.0f;
                    }
                }
            }
        }
        __syncthreads();

        // ---- phase 2: taps from LDS (no boundary branches needed) ----
        int lix = min(max(x0 - bx0, 0), ex - 2);   // clamp = LDS safety only
        int liy = min(max(y0 - by0, 0), ey - 2);
        int liz = min(max(z0 - bz0, 0), ez - 2);
        int pl   = ey * ldw;
        int base = (liz * ey + liy) * ldw + lix;
        float v000 = stage[base],            v001 = stage[base + 1];
        float v010 = stage[base + ldw],      v011 = stage[base + ldw + 1];
        float v100 = stage[base + pl],       v101 = stage[base + pl + 1];
        float v110 = stage[base + pl + ldw], v111 = stage[base + pl + ldw + 1];

        float c00 = fmaf(wx, v001 - v000, v000);
        float c01 = fmaf(wx, v011 - v010, v010);
        float c10 = fmaf(wx, v101 - v100, v100);
        float c11 = fmaf(wx, v111 - v110, v110);
        float c0  = fmaf(wy, c01 - c00, c00);
        float c1  = fmaf(wy, c11 - c10, c10);
        acc = fmaf(wz, c1 - c0, c0);
    } else {
        // ---- fallback: direct gather (block-uniform branch) ----
        bool all_in = ((unsigned)x0 < (unsigned)(Wv-1)) &
                      ((unsigned)y0 < (unsigned)(Hv-1)) &
                      ((unsigned)z0 < (unsigned)(Dv-1));
        if (all_in) {
            const float* p = sb + ((z0*Hv + y0)*Wv + x0);
            const float* q = p + Hv*Wv;
            float2 v00 = ld2(p);
            float2 v01 = ld2(p + Wv);
            float2 v10 = ld2(q);
            float2 v11 = ld2(q + Wv);
            float c00 = fmaf(wx, v00.y - v00.x, v00.x);
            float c01 = fmaf(wx, v01.y - v01.x, v01.x);
            float c10 = fmaf(wx, v10.y - v10.x, v10.x);
            float c11 = fmaf(wx, v11.y - v11.x, v11.x);
            float c0  = fmaf(wy, c01 - c00, c00);
            float c1  = fmaf(wy, c11 - c10, c10);
            acc = fmaf(wz, c1 - c0, c0);
        } else {
            int x1 = x0 + 1, y1 = y0 + 1, z1 = z0 + 1;
            bool all_out = (x1 < 0) | (x0 >= Wv) | (y1 < 0) | (y0 >= Hv) | (z1 < 0) | (z0 >= Dv);
            if (!all_out) {
                auto gather = [&](int zz, int yy, int xx) -> float {
                    bool valid = ((unsigned)xx < (unsigned)Wv) &
                                 ((unsigned)yy < (unsigned)Hv) &
                                 ((unsigned)zz < (unsigned)Dv);
                    int xi = min(max(xx, 0), Wv-1);
                    int yi = min(max(yy, 0), Hv-1);
                    int zi = min(max(zz, 0), Dv-1);
                    float val = sb[(zi*Hv + yi)*Wv + xi];
                    return valid ? val : 0.0f;
                };
                float owx = 1.0f - wx, owy = 1.0f - wy, owz = 1.0f - wz;
                acc  = gather(z0, y0, x0) * (owz*owy*owx);
                acc += gather(z0, y0, x0+1) * (owz*owy*wx);
                acc += gather(z0, y0+1, x0) * (owz*wy*owx);
                acc += gather(z0, y0+1, x0+1) * (owz*wy*wx);
                acc += gather(z0+1, y0, x0) * (wz*owy*owx);
                acc += gather(z0+1, y0, x0+1) * (wz*owy*wx);
                acc += gather(z0+1, y0+1, x0) * (wz*wy*owx);
                acc += gather(z0+1, y0+1, x0+1) * (wz*wy*wx);
            }
        }
    }

    // ---- phase 3: LDS transpose -> fully-coalesced stores (R7) ----
    int s = lx + (ly << 4) + (lz << 7);
    tileO[s ^ (lz << 2)] = acc;
    __syncthreads();

    float v = tileO[t ^ (((t >> 7) & 3) << 2)];

    int w2 = W0 + (t & 15);
    int h2 = H0 + ((t >> 4) & 7);
    int z2 = Z0 + (t >> 7);
    __builtin_nontemporal_store(v, &out[((size_t)(b*Dv + z2)*Hv + h2)*Wv + w2]);
}

extern "C" void kernel_launch(void* const* d_in, const int* in_sizes, int n_in,
                              void* d_out, int out_size, void* d_ws, size_t ws_size,
                              hipStream_t stream) {
    const float* src       = (const float*)d_in[0];
    const float* affine    = (const float*)d_in[1];
    const float* scale     = (const float*)d_in[2];
    const float* translate = (const float*)d_in[3];
    const float* shear     = (const float*)d_in[4];

    float* out  = (float*)d_out;
    float* mats = out + NOUT;   // mat (24 floats) then inv_mat (24 floats)

    compose_mats_kernel<<<1, 64, 0, stream>>>(affine, scale, translate, shear, mats);

    dim3 grid(Wv/16, Hv/8, (Dv/4)*Bv);
    warp_kernel<<<grid, 512, 0, stream>>>(src, mats, out);
}

// Round 9
// 61.871 us; speedup vs baseline: 1.8418x; 1.8418x over previous
//
#include <hip/hip_runtime.h>
#include <math.h>

#define Bv 2
#define Dv 192
#define Hv 192
#define Wv 192
#define Nv (Dv*Hv*Wv)          // 7,077,888 voxels per batch
#define NOUT (Bv*Nv)           // 14,155,776 warped elements

// Output tile per block: 16(x) x 16(y) x 8(z) = 2048 outputs, 512 threads,
// 4 z-outputs per thread.
// Interior blocks: stage the tile's source bbox into LDS via
// __builtin_amdgcn_global_load_lds (no VGPR round-trip, ~0 staging VALU),
// rows of 32 floats, source-x pre-swizzled so taps are bank-spread (the LDS
// write side must stay linear -- global_load_lds writes base + lane*4).
// Non-interior blocks: proven direct-gather path (R7).
#define TLZ 8
#define SWID 32
#define SROWS 384              // 48 KB stage

__device__ __forceinline__ void mm3(const float a[3][3], const float b[3][3], float c[3][3]) {
#pragma unroll
    for (int i = 0; i < 3; ++i)
#pragma unroll
        for (int j = 0; j < 3; ++j)
            c[i][j] = a[i][0]*b[0][j] + a[i][1]*b[1][j] + a[i][2]*b[2][j];
}

__global__ void compose_mats_kernel(const float* __restrict__ affine,
                                    const float* __restrict__ scale,
                                    const float* __restrict__ translate,
                                    const float* __restrict__ shear,
                                    float* __restrict__ mats_out) {
    int b = threadIdx.x;
    if (b >= Bv) return;

    float ax = affine[b*3+0], ay = affine[b*3+1], az = affine[b*3+2];
    float cx = cosf(ax), sx = sinf(ax);
    float cy = cosf(ay), sy = sinf(ay);
    float cz = cosf(az), sz = sinf(az);

    // _mk_mat transposes the written rows -> these are the transposed matrices.
    float rx[3][3] = {{1.f,0.f,0.f},{0.f,cx,sx},{0.f,-sx,cx}};
    float ry[3][3] = {{cy,0.f,-sy},{0.f,1.f,0.f},{sy,0.f,cy}};
    float rz[3][3] = {{cz,sz,0.f},{-sz,cz,0.f},{0.f,0.f,1.f}};

    float t0 = tanf(shear[b*6+0]), t1 = tanf(shear[b*6+1]), t2 = tanf(shear[b*6+2]);
    float t3 = tanf(shear[b*6+3]), t4 = tanf(shear[b*6+4]), t5 = tanf(shear[b*6+5]);
    float sh[3][3] = {{1.f,t2,t4},{t0,1.f,t5},{t1,t3,1.f}};

    float s0 = scale[b*3+0], s1 = scale[b*3+1], s2 = scale[b*3+2];

    float m1[3][3], m2[3][3], m3s[3][3], mat3[3][3];
    mm3(ry, rx, m1);
    mm3(rz, m1, m2);
#pragma unroll
    for (int j = 0; j < 3; ++j) { m3s[0][j] = s0*m2[0][j]; m3s[1][j] = s1*m2[1][j]; m3s[2][j] = s2*m2[2][j]; }
    mm3(sh, m3s, mat3);

    float tr0 = translate[b*3+0], tr1 = translate[b*3+1], tr2 = translate[b*3+2];

    float a00 = mat3[0][0], a01 = mat3[0][1], a02 = mat3[0][2];
    float a10 = mat3[1][0], a11 = mat3[1][1], a12 = mat3[1][2];
    float a20 = mat3[2][0], a21 = mat3[2][1], a22 = mat3[2][2];
    float c00 =  (a11*a22 - a12*a21);
    float c01 = -(a10*a22 - a12*a20);
    float c02 =  (a10*a21 - a11*a20);
    float det = a00*c00 + a01*c01 + a02*c02;
    float rdet = 1.0f / det;
    float inv3[3][3];
    inv3[0][0] = c00*rdet;
    inv3[0][1] = (a02*a21 - a01*a22)*rdet;
    inv3[0][2] = (a01*a12 - a02*a11)*rdet;
    inv3[1][0] = c01*rdet;
    inv3[1][1] = (a00*a22 - a02*a20)*rdet;
    inv3[1][2] = (a02*a10 - a00*a12)*rdet;
    inv3[2][0] = c02*rdet;
    inv3[2][1] = (a01*a20 - a00*a21)*rdet;
    inv3[2][2] = (a00*a11 - a01*a10)*rdet;

    float* mo = mats_out + b*12;
#pragma unroll
    for (int i = 0; i < 3; ++i) {
        mo[i*4+0] = mat3[i][0]; mo[i*4+1] = mat3[i][1]; mo[i*4+2] = mat3[i][2];
    }
    mo[0*4+3] = tr0; mo[1*4+3] = tr1; mo[2*4+3] = tr2;

    float* io = mats_out + 24 + b*12;
#pragma unroll
    for (int i = 0; i < 3; ++i) {
        io[i*4+0] = inv3[i][0]; io[i*4+1] = inv3[i][1]; io[i*4+2] = inv3[i][2];
        io[i*4+3] = -(inv3[i][0]*tr0 + inv3[i][1]*tr1 + inv3[i][2]*tr2);
    }
}

// 8-byte load from a 4-byte-aligned address (single global_load_dwordx2).
__device__ __forceinline__ float2 ld2(const float* p) {
    float2 r;
    __builtin_memcpy(&r, p, 8);
    return r;
}

// Direct global->LDS, 4 bytes/lane. LDS dest is wave-uniform base + lane*4.
__device__ __forceinline__ void gld_lds4(const float* g, float* l) {
    __builtin_amdgcn_global_load_lds(
        (const __attribute__((address_space(1))) unsigned int*)g,
        (__attribute__((address_space(3))) unsigned int*)l, 4, 0, 0);
}

__global__ __launch_bounds__(512) void warp_kernel(const float* __restrict__ src,
                                                   const float* __restrict__ mats,
                                                   float* __restrict__ out) {
    __shared__ float stage[SROWS*SWID];   // 48 KB

    int t   = threadIdx.x;
    int lx  = t & 15;
    int ly  = (t >> 4) & 15;
    int lzt = t >> 8;               // 0..1 (4 z-outputs each)

    int W0 = blockIdx.x * 16;
    int H0 = blockIdx.y * 16;
    int zt = blockIdx.z;            // 0 .. (Dv/TLZ)*Bv - 1
    int b  = zt / (Dv/TLZ);         // uniform
    int Z0 = (zt % (Dv/TLZ)) * TLZ;

    const float* M = mats + b*12;   // uniform -> scalar loads
    float m00 = M[0], m01 = M[1],  m02 = M[2],  m03 = M[3];
    float m10 = M[4], m11 = M[5],  m12 = M[6],  m13 = M[7];
    float m20 = M[8], m21 = M[9],  m22 = M[10], m23 = M[11];

    float Cx = 96.0f*(m03 - m00 - m01 - m02) + 95.5f;
    float Cy = 96.0f*(m13 - m10 - m11 - m12) + 95.5f;
    float Cz = 96.0f*(m23 - m20 - m21 - m22) + 95.5f;

    const float* sb = src + (size_t)b * Nv;

    // ---- block-uniform source bbox (tile corners +- half extent) ----
    float bcx = W0 + 8.0f, bcy = H0 + 8.0f, bcz = Z0 + 4.0f;
    float cxv = fmaf(m00, bcx, fmaf(m01, bcy, fmaf(m02, bcz, Cx)));
    float cyv = fmaf(m10, bcx, fmaf(m11, bcy, fmaf(m12, bcz, Cy)));
    float czv = fmaf(m20, bcx, fmaf(m21, bcy, fmaf(m22, bcz, Cz)));
    float hxv = 7.5f*fabsf(m00) + 7.5f*fabsf(m01) + 3.5f*fabsf(m02);
    float hyv = 7.5f*fabsf(m10) + 7.5f*fabsf(m11) + 3.5f*fabsf(m12);
    float hzv = 7.5f*fabsf(m20) + 7.5f*fabsf(m21) + 3.5f*fabsf(m22);

    int bx0 = (int)floorf(cxv - hxv) - 1;
    int by0 = (int)floorf(cyv - hyv) - 1;
    int bz0 = (int)floorf(czv - hzv) - 1;
    int ex  = (int)floorf(cxv + hxv) + 3 - bx0;   // taps need +1; +1 margin
    int ey  = (int)floorf(cyv + hyv) + 3 - by0;
    int ez  = (int)floorf(czv + hzv) + 3 - bz0;
    int rows = ey * ez;

    bool interior = (ex <= SWID) && (rows <= SROWS-1) &&
                    (bx0 >= 0) && (bx0 + SWID <= Wv) &&
                    (by0 >= 0) && (by0 + ey  <= Hv) &&
                    (bz0 >= 0) && (bz0 + ez  <= Dv);

    int w = W0 + lx, h = H0 + ly;
    float fw = w + 0.5f, fh = h + 0.5f;
    float fz0 = Z0 + lzt*4 + 0.5f;
    float ixb = fmaf(m00, fw, fmaf(m01, fh, fmaf(m02, fz0, Cx)));
    float iyb = fmaf(m10, fw, fmaf(m11, fh, fmaf(m12, fz0, Cy)));
    float izb = fmaf(m20, fw, fmaf(m21, fh, fmaf(m22, fz0, Cz)));

    float acc[4];

    if (interior) {
        // ---- phase 1: stage bbox rows via global_load_lds ----
        // wave issues 64 lanes x 4B = 256B = rows (r0, r0+1), cols 0..31.
        // Source x pre-swizzled: col c holds src x = bx0 + (c ^ h(row)).
        int lane  = t & 63;
        int wvu   = __builtin_amdgcn_readfirstlane(t >> 6);  // 0..7
        int col   = lane & 31;
        int rhalf = lane >> 5;
        // incremental (dy, dz) for this lane's row (rowl = r0 + rhalf)
        int dy_t = 2*wvu + rhalf, dz_t = 0;
        while (dy_t >= ey) { dy_t -= ey; dz_t += 1; }   // <=3 iters (rowl<16)
        for (int r0 = 2*wvu; r0 < rows; r0 += 16) {
            int rl  = r0 + rhalf;
            int dzc = min(dz_t, ez-1);                  // odd-rows junk guard
            int gx  = bx0 + (col ^ ((rl & 7) << 2));
            int gidx = ((bz0 + dzc)*Hv + (by0 + dy_t))*Wv + gx;
            gld_lds4(sb + gidx, &stage[r0*SWID]);
            dy_t += 16;
            while (dy_t >= ey) { dy_t -= ey; dz_t += 1; }
        }
        asm volatile("s_waitcnt vmcnt(0)" ::: "memory");
        __syncthreads();

        // ---- phase 2: taps from LDS (all guaranteed in-bounds) ----
#pragma unroll
        for (int zi = 0; zi < 4; ++zi) {
            float ix = fmaf(m02, (float)zi, ixb);
            float iy = fmaf(m12, (float)zi, iyb);
            float iz = fmaf(m22, (float)zi, izb);
            float flx = floorf(ix), fly = floorf(iy), flz = floorf(iz);
            float wx = ix - flx, wy = iy - fly, wz = iz - flz;
            int lix = min(max((int)flx - bx0, 0), ex-2);   // paranoia clamps
            int liy = min(max((int)fly - by0, 0), ey-2);
            int liz = min(max((int)flz - bz0, 0), ez-2);
            int r00 = liz*ey + liy;
            int r01 = r00 + 1;
            int r10 = r00 + ey;
            int r11 = r10 + 1;
            int x1 = lix + 1;
            float v000 = stage[r00*SWID + (lix ^ ((r00&7)<<2))];
            float v001 = stage[r00*SWID + (x1  ^ ((r00&7)<<2))];
            float v010 = stage[r01*SWID + (lix ^ ((r01&7)<<2))];
            float v011 = stage[r01*SWID + (x1  ^ ((r01&7)<<2))];
            float v100 = stage[r10*SWID + (lix ^ ((r10&7)<<2))];
            float v101 = stage[r10*SWID + (x1  ^ ((r10&7)<<2))];
            float v110 = stage[r11*SWID + (lix ^ ((r11&7)<<2))];
            float v111 = stage[r11*SWID + (x1  ^ ((r11&7)<<2))];
            float c00 = fmaf(wx, v001 - v000, v000);
            float c01 = fmaf(wx, v011 - v010, v010);
            float c10 = fmaf(wx, v101 - v100, v100);
            float c11 = fmaf(wx, v111 - v110, v110);
            float c0  = fmaf(wy, c01 - c00, c00);
            float c1  = fmaf(wy, c11 - c10, c10);
            acc[zi] = fmaf(wz, c1 - c0, c0);
        }
    } else {
        // ---- fallback: direct gather (block-uniform; R7 path) ----
#pragma unroll
        for (int zi = 0; zi < 4; ++zi) {
            float ix = fmaf(m02, (float)zi, ixb);
            float iy = fmaf(m12, (float)zi, iyb);
            float iz = fmaf(m22, (float)zi, izb);
            float flx = floorf(ix), fly = floorf(iy), flz = floorf(iz);
            float wx = ix - flx, wy = iy - fly, wz = iz - flz;
            int x0 = (int)flx, y0 = (int)fly, z0 = (int)flz;

            float a = 0.0f;
            bool all_in = ((unsigned)x0 < (unsigned)(Wv-1)) &
                          ((unsigned)y0 < (unsigned)(Hv-1)) &
                          ((unsigned)z0 < (unsigned)(Dv-1));
            if (all_in) {
                const float* p = sb + ((z0*Hv + y0)*Wv + x0);
                const float* q = p + Hv*Wv;
                float2 v00 = ld2(p);
                float2 v01 = ld2(p + Wv);
                float2 v10 = ld2(q);
                float2 v11 = ld2(q + Wv);
                float c00 = fmaf(wx, v00.y - v00.x, v00.x);
                float c01 = fmaf(wx, v01.y - v01.x, v01.x);
                float c10 = fmaf(wx, v10.y - v10.x, v10.x);
                float c11 = fmaf(wx, v11.y - v11.x, v11.x);
                float c0  = fmaf(wy, c01 - c00, c00);
                float c1  = fmaf(wy, c11 - c10, c10);
                a = fmaf(wz, c1 - c0, c0);
            } else {
                int x1 = x0 + 1, y1 = y0 + 1, z1 = z0 + 1;
                bool all_out = (x1 < 0) | (x0 >= Wv) | (y1 < 0) | (y0 >= Hv) | (z1 < 0) | (z0 >= Dv);
                if (!all_out) {
                    auto gather = [&](int zz, int yy, int xx) -> float {
                        bool valid = ((unsigned)xx < (unsigned)Wv) &
                                     ((unsigned)yy < (unsigned)Hv) &
                                     ((unsigned)zz < (unsigned)Dv);
                        int xi = min(max(xx, 0), Wv-1);
                        int yi = min(max(yy, 0), Hv-1);
                        int zi2 = min(max(zz, 0), Dv-1);
                        float val = sb[(zi2*Hv + yi)*Wv + xi];
                        return valid ? val : 0.0f;
                    };
                    float owx = 1.0f - wx, owy = 1.0f - wy, owz = 1.0f - wz;
                    a  = gather(z0, y0, x0) * (owz*owy*owx);
                    a += gather(z0, y0, x1) * (owz*owy*wx);
                    a += gather(z0, y1, x0) * (owz*wy*owx);
                    a += gather(z0, y1, x1) * (owz*wy*wx);
                    a += gather(z1, y0, x0) * (wz*owy*owx);
                    a += gather(z1, y0, x1) * (wz*owy*wx);
                    a += gather(z1, y1, x0) * (wz*wy*owx);
                    a += gather(z1, y1, x1) * (wz*wy*wx);
                }
            }
            acc[zi] = a;
        }
    }

    // ---- stores: 16-wide x rows -> full 64B lines, naturally coalesced ----
#pragma unroll
    for (int zi = 0; zi < 4; ++zi) {
        int z = Z0 + lzt*4 + zi;
        __builtin_nontemporal_store(acc[zi], &out[((size_t)(b*Dv + z)*Hv + h)*Wv + w]);
    }
}

extern "C" void kernel_launch(void* const* d_in, const int* in_sizes, int n_in,
                              void* d_out, int out_size, void* d_ws, size_t ws_size,
                              hipStream_t stream) {
    const float* src       = (const float*)d_in[0];
    const float* affine    = (const float*)d_in[1];
    const float* scale     = (const float*)d_in[2];
    const float* translate = (const float*)d_in[3];
    const float* shear     = (const float*)d_in[4];

    float* out  = (float*)d_out;
    float* mats = out + NOUT;   // mat (24 floats) then inv_mat (24 floats)

    compose_mats_kernel<<<1, 64, 0, stream>>>(affine, scale, translate, shear, mats);

    dim3 grid(Wv/16, Hv/16, (Dv/TLZ)*Bv);
    warp_kernel<<<grid, 512, 0, stream>>>(src, mats, out);
}

// Round 10
// 59.322 us; speedup vs baseline: 1.9210x; 1.0430x over previous
//
#include <hip/hip_runtime.h>
#include <math.h>

#define Bv 2
#define Dv 192
#define Hv 192
#define Wv 192
#define Nv (Dv*Hv*Wv)          // 7,077,888 voxels per batch
#define NOUT (Bv*Nv)           // 14,155,776 warped elements

// Output tile per block: 16(x) x 16(y) x 8(z) = 2048 outputs, 512 threads,
// 4 z-outputs per thread.
// Interior blocks: stage source bbox rows (32 floats wide, UNSWIZZLED) into
// LDS via global_load_lds size=16 (zero staging VALU), then taps are
// stage[base]/+1/+32/+33 -> ds_read2_b32 pairs, ~5 VALU addressing/output.
// Tap bank conflicts (bank = lix mod 32, ~4-8 way) accepted: DS pipe is not
// the critical path; TA line-serialization (the measured 58us wall) is.
// Non-interior blocks (bbox OOB or rows>440): proven direct-gather path.
#define TLZ 8
#define SWID 32
#define SROWS 448              // 56 KB stage
#define ROWCAP 440             // leave an 8-row chunk of slack

__device__ __forceinline__ void mm3(const float a[3][3], const float b[3][3], float c[3][3]) {
#pragma unroll
    for (int i = 0; i < 3; ++i)
#pragma unroll
        for (int j = 0; j < 3; ++j)
            c[i][j] = a[i][0]*b[0][j] + a[i][1]*b[1][j] + a[i][2]*b[2][j];
}

__global__ void compose_mats_kernel(const float* __restrict__ affine,
                                    const float* __restrict__ scale,
                                    const float* __restrict__ translate,
                                    const float* __restrict__ shear,
                                    float* __restrict__ mats_out) {
    int b = threadIdx.x;
    if (b >= Bv) return;

    float ax = affine[b*3+0], ay = affine[b*3+1], az = affine[b*3+2];
    float cx = cosf(ax), sx = sinf(ax);
    float cy = cosf(ay), sy = sinf(ay);
    float cz = cosf(az), sz = sinf(az);

    // _mk_mat transposes the written rows -> these are the transposed matrices.
    float rx[3][3] = {{1.f,0.f,0.f},{0.f,cx,sx},{0.f,-sx,cx}};
    float ry[3][3] = {{cy,0.f,-sy},{0.f,1.f,0.f},{sy,0.f,cy}};
    float rz[3][3] = {{cz,sz,0.f},{-sz,cz,0.f},{0.f,0.f,1.f}};

    float t0 = tanf(shear[b*6+0]), t1 = tanf(shear[b*6+1]), t2 = tanf(shear[b*6+2]);
    float t3 = tanf(shear[b*6+3]), t4 = tanf(shear[b*6+4]), t5 = tanf(shear[b*6+5]);
    float sh[3][3] = {{1.f,t2,t4},{t0,1.f,t5},{t1,t3,1.f}};

    float s0 = scale[b*3+0], s1 = scale[b*3+1], s2 = scale[b*3+2];

    float m1[3][3], m2[3][3], m3s[3][3], mat3[3][3];
    mm3(ry, rx, m1);
    mm3(rz, m1, m2);
#pragma unroll
    for (int j = 0; j < 3; ++j) { m3s[0][j] = s0*m2[0][j]; m3s[1][j] = s1*m2[1][j]; m3s[2][j] = s2*m2[2][j]; }
    mm3(sh, m3s, mat3);

    float tr0 = translate[b*3+0], tr1 = translate[b*3+1], tr2 = translate[b*3+2];

    float a00 = mat3[0][0], a01 = mat3[0][1], a02 = mat3[0][2];
    float a10 = mat3[1][0], a11 = mat3[1][1], a12 = mat3[1][2];
    float a20 = mat3[2][0], a21 = mat3[2][1], a22 = mat3[2][2];
    float c00 =  (a11*a22 - a12*a21);
    float c01 = -(a10*a22 - a12*a20);
    float c02 =  (a10*a21 - a11*a20);
    float det = a00*c00 + a01*c01 + a02*c02;
    float rdet = 1.0f / det;
    float inv3[3][3];
    inv3[0][0] = c00*rdet;
    inv3[0][1] = (a02*a21 - a01*a22)*rdet;
    inv3[0][2] = (a01*a12 - a02*a11)*rdet;
    inv3[1][0] = c01*rdet;
    inv3[1][1] = (a00*a22 - a02*a20)*rdet;
    inv3[1][2] = (a02*a10 - a00*a12)*rdet;
    inv3[2][0] = c02*rdet;
    inv3[2][1] = (a01*a20 - a00*a21)*rdet;
    inv3[2][2] = (a00*a11 - a01*a10)*rdet;

    float* mo = mats_out + b*12;
#pragma unroll
    for (int i = 0; i < 3; ++i) {
        mo[i*4+0] = mat3[i][0]; mo[i*4+1] = mat3[i][1]; mo[i*4+2] = mat3[i][2];
    }
    mo[0*4+3] = tr0; mo[1*4+3] = tr1; mo[2*4+3] = tr2;

    float* io = mats_out + 24 + b*12;
#pragma unroll
    for (int i = 0; i < 3; ++i) {
        io[i*4+0] = inv3[i][0]; io[i*4+1] = inv3[i][1]; io[i*4+2] = inv3[i][2];
        io[i*4+3] = -(inv3[i][0]*tr0 + inv3[i][1]*tr1 + inv3[i][2]*tr2);
    }
}

// 8-byte load from a 4-byte-aligned address (single global_load_dwordx2).
__device__ __forceinline__ float2 ld2(const float* p) {
    float2 r;
    __builtin_memcpy(&r, p, 8);
    return r;
}

// Direct global->LDS, 16 bytes/lane (global_load_lds_dwordx4).
// LDS dest is wave-uniform base; lane l writes bytes [base+16l, base+16l+16).
__device__ __forceinline__ void gld_lds16(const float* g, float* l) {
    __builtin_amdgcn_global_load_lds(
        (const __attribute__((address_space(1))) unsigned int*)g,
        (__attribute__((address_space(3))) unsigned int*)l, 16, 0, 0);
}

__global__ __launch_bounds__(512) void warp_kernel(const float* __restrict__ src,
                                                   const float* __restrict__ mats,
                                                   float* __restrict__ out) {
    __shared__ float stage[SROWS*SWID];   // 56 KB

    int t   = threadIdx.x;
    int lx  = t & 15;
    int ly  = (t >> 4) & 15;
    int lzt = t >> 8;               // 0..1 (4 z-outputs each)

    int W0 = blockIdx.x * 16;
    int H0 = blockIdx.y * 16;
    int zt = blockIdx.z;            // 0 .. (Dv/TLZ)*Bv - 1
    int b  = zt / (Dv/TLZ);         // uniform
    int Z0 = (zt % (Dv/TLZ)) * TLZ;

    const float* M = mats + b*12;   // uniform -> scalar loads
    float m00 = M[0], m01 = M[1],  m02 = M[2],  m03 = M[3];
    float m10 = M[4], m11 = M[5],  m12 = M[6],  m13 = M[7];
    float m20 = M[8], m21 = M[9],  m22 = M[10], m23 = M[11];

    float Cx = 96.0f*(m03 - m00 - m01 - m02) + 95.5f;
    float Cy = 96.0f*(m13 - m10 - m11 - m12) + 95.5f;
    float Cz = 96.0f*(m23 - m20 - m21 - m22) + 95.5f;

    const float* sb = src + (size_t)b * Nv;

    // ---- block-uniform source bbox (tile corners +- half extent) ----
    float bcx = W0 + 8.0f, bcy = H0 + 8.0f, bcz = Z0 + 4.0f;
    float cxv = fmaf(m00, bcx, fmaf(m01, bcy, fmaf(m02, bcz, Cx)));
    float cyv = fmaf(m10, bcx, fmaf(m11, bcy, fmaf(m12, bcz, Cy)));
    float czv = fmaf(m20, bcx, fmaf(m21, bcy, fmaf(m22, bcz, Cz)));
    float hxv = 7.5f*fabsf(m00) + 7.5f*fabsf(m01) + 3.5f*fabsf(m02);
    float hyv = 7.5f*fabsf(m10) + 7.5f*fabsf(m11) + 3.5f*fabsf(m12);
    float hzv = 7.5f*fabsf(m20) + 7.5f*fabsf(m21) + 3.5f*fabsf(m22);

    int bx0 = ((int)floorf(cxv - hxv) - 1) & ~3;   // 16B-aligned staging
    int by0 = (int)floorf(cyv - hyv) - 1;
    int bz0 = (int)floorf(czv - hzv) - 1;
    int xmax = (int)floorf(cxv + hxv) + 2;         // last tap x
    int ey  = (int)floorf(cyv + hyv) + 3 - by0;
    int ez  = (int)floorf(czv + hzv) + 3 - bz0;
    int rows = ey * ez;

    bool interior = (xmax - bx0 + 1 <= SWID) && (rows <= ROWCAP) &&
                    (bx0 >= 0) && (bx0 + SWID <= Wv) &&
                    (by0 >= 0) && (by0 + ey  <= Hv) &&
                    (bz0 >= 0) && (bz0 + ez  <= Dv);

    int w = W0 + lx, h = H0 + ly;
    float fw = w + 0.5f, fh = h + 0.5f;
    float fz0 = Z0 + lzt*4 + 0.5f;

    float acc[4];

    if (interior) {
        // ---- phase 1: stage bbox rows via global_load_lds (issue first) ----
        // one instruction stages 8 rows x 32 floats; wave wvu covers rows
        // [wvu*8 + 64k, +8).
        int lane  = t & 63;
        int wvu   = __builtin_amdgcn_readfirstlane(t >> 6);  // 0..7
        int lrow8 = lane >> 3;          // row within the 8-row chunk
        int cblk  = (lane & 7) << 2;    // float col 0,4,..,28
        float rcp_ey = __builtin_amdgcn_rcpf((float)ey);
        int base0 = (bz0*Hv + by0)*Wv + bx0 + cblk;   // per-lane
        for (int r0 = wvu*8; r0 < rows; r0 += 64) {
            int rl = r0 + lrow8;
            int dz = (int)(((float)rl + 0.5f) * rcp_ey);
            dz = min(dz, ez-1);                        // overflow-row guard
            int dy = rl - dz*ey;
            int gidx = base0 + (dz*Hv + dy)*Wv;
            gld_lds16(sb + gidx, &stage[r0*SWID]);
        }

        // ---- per-thread coords (overlaps DMA) ----
        float ixb = fmaf(m00, fw, fmaf(m01, fh, fmaf(m02, fz0, Cx)));
        float iyb = fmaf(m10, fw, fmaf(m11, fh, fmaf(m12, fz0, Cy)));
        float izb = fmaf(m20, fw, fmaf(m21, fh, fmaf(m22, fz0, Cz)));

        asm volatile("s_waitcnt vmcnt(0)" ::: "memory");
        __syncthreads();

        // ---- phase 2: taps from LDS (unswizzled; ds_read2-friendly) ----
#pragma unroll
        for (int zi = 0; zi < 4; ++zi) {
            float ix = fmaf(m02, (float)zi, ixb);
            float iy = fmaf(m12, (float)zi, iyb);
            float iz = fmaf(m22, (float)zi, izb);
            float flx = floorf(ix), fly = floorf(iy), flz = floorf(iz);
            float wx = ix - flx, wy = iy - fly, wz = iz - flz;
            int lix = min(max((int)flx - bx0, 0), SWID-2);   // safety clamps
            int liy = min(max((int)fly - by0, 0), ey-2);
            int liz = min(max((int)flz - bz0, 0), ez-2);
            int base = (liz*ey + liy)*SWID + lix;
            int b1   = base + ey*SWID;
            float v000 = stage[base],        v001 = stage[base+1];
            float v010 = stage[base+SWID],   v011 = stage[base+SWID+1];
            float v100 = stage[b1],          v101 = stage[b1+1];
            float v110 = stage[b1+SWID],     v111 = stage[b1+SWID+1];
            float c00 = fmaf(wx, v001 - v000, v000);
            float c01 = fmaf(wx, v011 - v010, v010);
            float c10 = fmaf(wx, v101 - v100, v100);
            float c11 = fmaf(wx, v111 - v110, v110);
            float c0  = fmaf(wy, c01 - c00, c00);
            float c1  = fmaf(wy, c11 - c10, c10);
            acc[zi] = fmaf(wz, c1 - c0, c0);
        }
    } else {
        // ---- fallback: direct gather (block-uniform; R7 path) ----
        float ixb = fmaf(m00, fw, fmaf(m01, fh, fmaf(m02, fz0, Cx)));
        float iyb = fmaf(m10, fw, fmaf(m11, fh, fmaf(m12, fz0, Cy)));
        float izb = fmaf(m20, fw, fmaf(m21, fh, fmaf(m22, fz0, Cz)));
#pragma unroll
        for (int zi = 0; zi < 4; ++zi) {
            float ix = fmaf(m02, (float)zi, ixb);
            float iy = fmaf(m12, (float)zi, iyb);
            float iz = fmaf(m22, (float)zi, izb);
            float flx = floorf(ix), fly = floorf(iy), flz = floorf(iz);
            float wx = ix - flx, wy = iy - fly, wz = iz - flz;
            int x0 = (int)flx, y0 = (int)fly, z0 = (int)flz;

            float a = 0.0f;
            bool all_in = ((unsigned)x0 < (unsigned)(Wv-1)) &
                          ((unsigned)y0 < (unsigned)(Hv-1)) &
                          ((unsigned)z0 < (unsigned)(Dv-1));
            if (all_in) {
                const float* p = sb + ((z0*Hv + y0)*Wv + x0);
                const float* q = p + Hv*Wv;
                float2 v00 = ld2(p);
                float2 v01 = ld2(p + Wv);
                float2 v10 = ld2(q);
                float2 v11 = ld2(q + Wv);
                float c00 = fmaf(wx, v00.y - v00.x, v00.x);
                float c01 = fmaf(wx, v01.y - v01.x, v01.x);
                float c10 = fmaf(wx, v10.y - v10.x, v10.x);
                float c11 = fmaf(wx, v11.y - v11.x, v11.x);
                float c0  = fmaf(wy, c01 - c00, c00);
                float c1  = fmaf(wy, c11 - c10, c10);
                a = fmaf(wz, c1 - c0, c0);
            } else {
                int x1 = x0 + 1, y1 = y0 + 1, z1 = z0 + 1;
                bool all_out = (x1 < 0) | (x0 >= Wv) | (y1 < 0) | (y0 >= Hv) | (z1 < 0) | (z0 >= Dv);
                if (!all_out) {
                    auto gather = [&](int zz, int yy, int xx) -> float {
                        bool valid = ((unsigned)xx < (unsigned)Wv) &
                                     ((unsigned)yy < (unsigned)Hv) &
                                     ((unsigned)zz < (unsigned)Dv);
                        int xi = min(max(xx, 0), Wv-1);
                        int yi = min(max(yy, 0), Hv-1);
                        int zi2 = min(max(zz, 0), Dv-1);
                        float val = sb[(zi2*Hv + yi)*Wv + xi];
                        return valid ? val : 0.0f;
                    };
                    float owx = 1.0f - wx, owy = 1.0f - wy, owz = 1.0f - wz;
                    a  = gather(z0, y0, x0) * (owz*owy*owx);
                    a += gather(z0, y0, x1) * (owz*owy*wx);
                    a += gather(z0, y1, x0) * (owz*wy*owx);
                    a += gather(z0, y1, x1) * (owz*wy*wx);
                    a += gather(z1, y0, x0) * (wz*owy*owx);
                    a += gather(z1, y0, x1) * (wz*owy*wx);
                    a += gather(z1, y1, x0) * (wz*wy*owx);
                    a += gather(z1, y1, x1) * (wz*wy*wx);
                }
            }
            acc[zi] = a;
        }
    }

    // ---- stores: 16-wide x rows -> full 64B lines, naturally coalesced ----
#pragma unroll
    for (int zi = 0; zi < 4; ++zi) {
        int z = Z0 + lzt*4 + zi;
        __builtin_nontemporal_store(acc[zi], &out[((size_t)(b*Dv + z)*Hv + h)*Wv + w]);
    }
}

extern "C" void kernel_launch(void* const* d_in, const int* in_sizes, int n_in,
                              void* d_out, int out_size, void* d_ws, size_t ws_size,
                              hipStream_t stream) {
    const float* src       = (const float*)d_in[0];
    const float* affine    = (const float*)d_in[1];
    const float* scale     = (const float*)d_in[2];
    const float* translate = (const float*)d_in[3];
    const float* shear     = (const float*)d_in[4];

    float* out  = (float*)d_out;
    float* mats = out + NOUT;   // mat (24 floats) then inv_mat (24 floats)

    compose_mats_kernel<<<1, 64, 0, stream>>>(affine, scale, translate, shear, mats);

    dim3 grid(Wv/16, Hv/16, (Dv/TLZ)*Bv);
    warp_kernel<<<grid, 512, 0, stream>>>(src, mats, out);
}

// Round 11
// 52.484 us; speedup vs baseline: 2.1713x; 1.1303x over previous
//
#include <hip/hip_runtime.h>
#include <math.h>

#define Bv 2
#define Dv 192
#define Hv 192
#define Wv 192
#define Nv (Dv*Hv*Wv)          // 7,077,888 voxels per batch
#define NOUT (Bv*Nv)           // 14,155,776 warped elements

// Output tile per block: 16(x) x 16(y) x 8(z) = 2048 outputs, 512 threads,
// 4 z-outputs per thread.
// Staged path: source bbox -> LDS via global_load_lds size=4, one ROW-PAIR
// (2x32 floats) per instruction, stored plane-major with pair stride 68
// floats (64 data + 4 pad). Row-pair base mod 32 = 4*pair + (4nP+4)*plane ->
// taps spread across all 32 banks (~2-way, free) with ZERO per-tap swizzle
// VALU; x-pairs stay adjacent so ds_read2_b32 fusion survives.
// LDS = 52KB -> 3 blocks/CU (75% occ) so stage drains overlap compute.
// Non-interior / oversized-bbox blocks: proven direct-gather path (R7).
#define TLZ 8
#define SWID 32
#define CAPF 13312             // 52 KB stage (floats)

__device__ __forceinline__ void mm3(const float a[3][3], const float b[3][3], float c[3][3]) {
#pragma unroll
    for (int i = 0; i < 3; ++i)
#pragma unroll
        for (int j = 0; j < 3; ++j)
            c[i][j] = a[i][0]*b[0][j] + a[i][1]*b[1][j] + a[i][2]*b[2][j];
}

__global__ void compose_mats_kernel(const float* __restrict__ affine,
                                    const float* __restrict__ scale,
                                    const float* __restrict__ translate,
                                    const float* __restrict__ shear,
                                    float* __restrict__ mats_out) {
    int b = threadIdx.x;
    if (b >= Bv) return;

    float ax = affine[b*3+0], ay = affine[b*3+1], az = affine[b*3+2];
    float cx = cosf(ax), sx = sinf(ax);
    float cy = cosf(ay), sy = sinf(ay);
    float cz = cosf(az), sz = sinf(az);

    // _mk_mat transposes the written rows -> these are the transposed matrices.
    float rx[3][3] = {{1.f,0.f,0.f},{0.f,cx,sx},{0.f,-sx,cx}};
    float ry[3][3] = {{cy,0.f,-sy},{0.f,1.f,0.f},{sy,0.f,cy}};
    float rz[3][3] = {{cz,sz,0.f},{-sz,cz,0.f},{0.f,0.f,1.f}};

    float t0 = tanf(shear[b*6+0]), t1 = tanf(shear[b*6+1]), t2 = tanf(shear[b*6+2]);
    float t3 = tanf(shear[b*6+3]), t4 = tanf(shear[b*6+4]), t5 = tanf(shear[b*6+5]);
    float sh[3][3] = {{1.f,t2,t4},{t0,1.f,t5},{t1,t3,1.f}};

    float s0 = scale[b*3+0], s1 = scale[b*3+1], s2 = scale[b*3+2];

    float m1[3][3], m2[3][3], m3s[3][3], mat3[3][3];
    mm3(ry, rx, m1);
    mm3(rz, m1, m2);
#pragma unroll
    for (int j = 0; j < 3; ++j) { m3s[0][j] = s0*m2[0][j]; m3s[1][j] = s1*m2[1][j]; m3s[2][j] = s2*m2[2][j]; }
    mm3(sh, m3s, mat3);

    float tr0 = translate[b*3+0], tr1 = translate[b*3+1], tr2 = translate[b*3+2];

    float a00 = mat3[0][0], a01 = mat3[0][1], a02 = mat3[0][2];
    float a10 = mat3[1][0], a11 = mat3[1][1], a12 = mat3[1][2];
    float a20 = mat3[2][0], a21 = mat3[2][1], a22 = mat3[2][2];
    float c00 =  (a11*a22 - a12*a21);
    float c01 = -(a10*a22 - a12*a20);
    float c02 =  (a10*a21 - a11*a20);
    float det = a00*c00 + a01*c01 + a02*c02;
    float rdet = 1.0f / det;
    float inv3[3][3];
    inv3[0][0] = c00*rdet;
    inv3[0][1] = (a02*a21 - a01*a22)*rdet;
    inv3[0][2] = (a01*a12 - a02*a11)*rdet;
    inv3[1][0] = c01*rdet;
    inv3[1][1] = (a00*a22 - a02*a20)*rdet;
    inv3[1][2] = (a02*a10 - a00*a12)*rdet;
    inv3[2][0] = c02*rdet;
    inv3[2][1] = (a01*a20 - a00*a21)*rdet;
    inv3[2][2] = (a00*a11 - a01*a10)*rdet;

    float* mo = mats_out + b*12;
#pragma unroll
    for (int i = 0; i < 3; ++i) {
        mo[i*4+0] = mat3[i][0]; mo[i*4+1] = mat3[i][1]; mo[i*4+2] = mat3[i][2];
    }
    mo[0*4+3] = tr0; mo[1*4+3] = tr1; mo[2*4+3] = tr2;

    float* io = mats_out + 24 + b*12;
#pragma unroll
    for (int i = 0; i < 3; ++i) {
        io[i*4+0] = inv3[i][0]; io[i*4+1] = inv3[i][1]; io[i*4+2] = inv3[i][2];
        io[i*4+3] = -(inv3[i][0]*tr0 + inv3[i][1]*tr1 + inv3[i][2]*tr2);
    }
}

// 8-byte load from a 4-byte-aligned address (single global_load_dwordx2).
__device__ __forceinline__ float2 ld2(const float* p) {
    float2 r;
    __builtin_memcpy(&r, p, 8);
    return r;
}

// Direct global->LDS, 4 bytes/lane: lane l reads its own global addr and
// writes LDS float (base + l). 64 lanes = one 2x32-float row-pair.
__device__ __forceinline__ void gld_lds4(const float* g, float* l) {
    __builtin_amdgcn_global_load_lds(
        (const __attribute__((address_space(1))) unsigned int*)g,
        (__attribute__((address_space(3))) unsigned int*)l, 4, 0, 0);
}

__global__ __launch_bounds__(512) void warp_kernel(const float* __restrict__ src,
                                                   const float* __restrict__ mats,
                                                   float* __restrict__ out) {
    __shared__ float stage[CAPF];   // 52 KB

    int t   = threadIdx.x;
    int lx  = t & 15;
    int ly  = (t >> 4) & 15;
    int lzt = t >> 8;               // 0..1 (4 z-outputs each)

    int W0 = blockIdx.x * 16;
    int H0 = blockIdx.y * 16;
    int zt = blockIdx.z;            // 0 .. (Dv/TLZ)*Bv - 1
    int b  = zt / (Dv/TLZ);         // uniform
    int Z0 = (zt % (Dv/TLZ)) * TLZ;

    const float* M = mats + b*12;   // uniform -> scalar loads
    float m00 = M[0], m01 = M[1],  m02 = M[2],  m03 = M[3];
    float m10 = M[4], m11 = M[5],  m12 = M[6],  m13 = M[7];
    float m20 = M[8], m21 = M[9],  m22 = M[10], m23 = M[11];

    float Cx = 96.0f*(m03 - m00 - m01 - m02) + 95.5f;
    float Cy = 96.0f*(m13 - m10 - m11 - m12) + 95.5f;
    float Cz = 96.0f*(m23 - m20 - m21 - m22) + 95.5f;

    const float* sb = src + (size_t)b * Nv;

    // ---- block-uniform source bbox (tile corners +- half extent) ----
    float bcx = W0 + 8.0f, bcy = H0 + 8.0f, bcz = Z0 + 4.0f;
    float cxv = fmaf(m00, bcx, fmaf(m01, bcy, fmaf(m02, bcz, Cx)));
    float cyv = fmaf(m10, bcx, fmaf(m11, bcy, fmaf(m12, bcz, Cy)));
    float czv = fmaf(m20, bcx, fmaf(m21, bcy, fmaf(m22, bcz, Cz)));
    float hxv = 7.5f*fabsf(m00) + 7.5f*fabsf(m01) + 3.5f*fabsf(m02);
    float hyv = 7.5f*fabsf(m10) + 7.5f*fabsf(m11) + 3.5f*fabsf(m12);
    float hzv = 7.5f*fabsf(m20) + 7.5f*fabsf(m21) + 3.5f*fabsf(m22);

    int bx0 = ((int)floorf(cxv - hxv) - 1) & ~3;
    int by0 = (int)floorf(cyv - hyv) - 1;
    int bz0 = (int)floorf(czv - hzv) - 1;
    int xmax = (int)floorf(cxv + hxv) + 2;         // last tap x
    int ey  = (int)floorf(cyv + hyv) + 3 - by0;
    int ez  = (int)floorf(czv + hzv) + 3 - bz0;

    int nP  = (ey + 1) >> 1;        // row-pairs per plane
    int PST = 68*nP + 4;            // plane stride (floats); +4 shifts banks/plane

    bool interior = (PST*ez <= CAPF) && (xmax - bx0 + 1 <= SWID) &&
                    (bx0 >= 0) && (bx0 + SWID   <= Wv) &&
                    (by0 >= 0) && (by0 + 2*nP   <= Hv) &&
                    (bz0 >= 0) && (bz0 + ez     <= Dv);

    int w = W0 + lx, h = H0 + ly;
    float fw = w + 0.5f, fh = h + 0.5f;
    float fz0 = Z0 + lzt*4 + 0.5f;

    float acc[4];

    if (interior) {
        // ---- phase 1: stage bbox via row-pair DMA (issue first) ----
        int lane = t & 63;
        int wvu  = __builtin_amdgcn_readfirstlane(t >> 6);  // 0..7
        int lrow = lane >> 5;          // row within pair
        int col  = lane & 31;
        int srcb = (bz0*Hv + by0)*Wv + bx0 + lrow*Wv + col;   // per-lane
        for (int dz = wvu; dz < ez; dz += 8) {
            int sp = srcb + dz*(Hv*Wv);     // uniform dz -> s_mul + v_add
            int lb = dz*PST;                // wave-uniform
            for (int j = 0; j < nP; ++j) {
                gld_lds4(sb + sp, &stage[lb + j*68]);
                sp += 2*Wv;
            }
        }

        // ---- per-thread coords (overlaps DMA) ----
        float ixb = fmaf(m00, fw, fmaf(m01, fh, fmaf(m02, fz0, Cx)));
        float iyb = fmaf(m10, fw, fmaf(m11, fh, fmaf(m12, fz0, Cy)));
        float izb = fmaf(m20, fw, fmaf(m21, fh, fmaf(m22, fz0, Cz)));

        asm volatile("s_waitcnt vmcnt(0)" ::: "memory");
        __syncthreads();

        // ---- phase 2: taps from LDS (pair-stride-68 layout) ----
#pragma unroll
        for (int zi = 0; zi < 4; ++zi) {
            float ix = fmaf(m02, (float)zi, ixb);
            float iy = fmaf(m12, (float)zi, iyb);
            float iz = fmaf(m22, (float)zi, izb);
            float flx = floorf(ix), fly = floorf(iy), flz = floorf(iz);
            float wx = ix - flx, wy = iy - fly, wz = iz - flz;
            int lix = min(max((int)flx - bx0, 0), SWID-2);     // safety clamps
            int liy = min(max((int)fly - by0, 0), 2*nP-2);
            int liz = min(max((int)flz - bz0, 0), ez-2);
            int liy1 = liy + 1;
            int o00 = liz*PST + (liy  >> 1)*68 + ((liy  & 1) << 5) + lix;
            int o01 = liz*PST + (liy1 >> 1)*68 + ((liy1 & 1) << 5) + lix;
            int o10 = o00 + PST;
            int o11 = o01 + PST;
            float v000 = stage[o00], v001 = stage[o00+1];
            float v010 = stage[o01], v011 = stage[o01+1];
            float v100 = stage[o10], v101 = stage[o10+1];
            float v110 = stage[o11], v111 = stage[o11+1];
            float c00 = fmaf(wx, v001 - v000, v000);
            float c01 = fmaf(wx, v011 - v010, v010);
            float c10 = fmaf(wx, v101 - v100, v100);
            float c11 = fmaf(wx, v111 - v110, v110);
            float c0  = fmaf(wy, c01 - c00, c00);
            float c1  = fmaf(wy, c11 - c10, c10);
            acc[zi] = fmaf(wz, c1 - c0, c0);
        }
    } else {
        // ---- fallback: direct gather (block-uniform; R7 path) ----
        float ixb = fmaf(m00, fw, fmaf(m01, fh, fmaf(m02, fz0, Cx)));
        float iyb = fmaf(m10, fw, fmaf(m11, fh, fmaf(m12, fz0, Cy)));
        float izb = fmaf(m20, fw, fmaf(m21, fh, fmaf(m22, fz0, Cz)));
#pragma unroll
        for (int zi = 0; zi < 4; ++zi) {
            float ix = fmaf(m02, (float)zi, ixb);
            float iy = fmaf(m12, (float)zi, iyb);
            float iz = fmaf(m22, (float)zi, izb);
            float flx = floorf(ix), fly = floorf(iy), flz = floorf(iz);
            float wx = ix - flx, wy = iy - fly, wz = iz - flz;
            int x0 = (int)flx, y0 = (int)fly, z0 = (int)flz;

            float a = 0.0f;
            bool all_in = ((unsigned)x0 < (unsigned)(Wv-1)) &
                          ((unsigned)y0 < (unsigned)(Hv-1)) &
                          ((unsigned)z0 < (unsigned)(Dv-1));
            if (all_in) {
                const float* p = sb + ((z0*Hv + y0)*Wv + x0);
                const float* q = p + Hv*Wv;
                float2 v00 = ld2(p);
                float2 v01 = ld2(p + Wv);
                float2 v10 = ld2(q);
                float2 v11 = ld2(q + Wv);
                float c00 = fmaf(wx, v00.y - v00.x, v00.x);
                float c01 = fmaf(wx, v01.y - v01.x, v01.x);
                float c10 = fmaf(wx, v10.y - v10.x, v10.x);
                float c11 = fmaf(wx, v11.y - v11.x, v11.x);
                float c0  = fmaf(wy, c01 - c00, c00);
                float c1  = fmaf(wy, c11 - c10, c10);
                a = fmaf(wz, c1 - c0, c0);
            } else {
                int x1 = x0 + 1, y1 = y0 + 1, z1 = z0 + 1;
                bool all_out = (x1 < 0) | (x0 >= Wv) | (y1 < 0) | (y0 >= Hv) | (z1 < 0) | (z0 >= Dv);
                if (!all_out) {
                    auto gather = [&](int zz, int yy, int xx) -> float {
                        bool valid = ((unsigned)xx < (unsigned)Wv) &
                                     ((unsigned)yy < (unsigned)Hv) &
                                     ((unsigned)zz < (unsigned)Dv);
                        int xi = min(max(xx, 0), Wv-1);
                        int yi = min(max(yy, 0), Hv-1);
                        int zi2 = min(max(zz, 0), Dv-1);
                        float val = sb[(zi2*Hv + yi)*Wv + xi];
                        return valid ? val : 0.0f;
                    };
                    float owx = 1.0f - wx, owy = 1.0f - wy, owz = 1.0f - wz;
                    a  = gather(z0, y0, x0) * (owz*owy*owx);
                    a += gather(z0, y0, x1) * (owz*owy*wx);
                    a += gather(z0, y1, x0) * (owz*wy*owx);
                    a += gather(z0, y1, x1) * (owz*wy*wx);
                    a += gather(z1, y0, x0) * (wz*owy*owx);
                    a += gather(z1, y0, x1) * (wz*owy*wx);
                    a += gather(z1, y1, x0) * (wz*wy*owx);
                    a += gather(z1, y1, x1) * (wz*wy*wx);
                }
            }
            acc[zi] = a;
        }
    }

    // ---- stores: 16-wide x rows -> full 64B lines, naturally coalesced ----
#pragma unroll
    for (int zi = 0; zi < 4; ++zi) {
        int z = Z0 + lzt*4 + zi;
        __builtin_nontemporal_store(acc[zi], &out[((size_t)(b*Dv + z)*Hv + h)*Wv + w]);
    }
}

extern "C" void kernel_launch(void* const* d_in, const int* in_sizes, int n_in,
                              void* d_out, int out_size, void* d_ws, size_t ws_size,
                              hipStream_t stream) {
    const float* src       = (const float*)d_in[0];
    const float* affine    = (const float*)d_in[1];
    const float* scale     = (const float*)d_in[2];
    const float* translate = (const float*)d_in[3];
    const float* shear     = (const float*)d_in[4];

    float* out  = (float*)d_out;
    float* mats = out + NOUT;   // mat (24 floats) then inv_mat (24 floats)

    compose_mats_kernel<<<1, 64, 0, stream>>>(affine, scale, translate, shear, mats);

    dim3 grid(Wv/16, Hv/16, (Dv/TLZ)*Bv);
    warp_kernel<<<grid, 512, 0, stream>>>(src, mats, out);
}

// Round 12
// 52.054 us; speedup vs baseline: 2.1892x; 1.0083x over previous
//
#include <hip/hip_runtime.h>
#include <math.h>

#define Bv 2
#define Dv 192
#define Hv 192
#define Wv 192
#define Nv (Dv*Hv*Wv)          // 7,077,888 voxels per batch
#define NOUT (Bv*Nv)           // 14,155,776 warped elements

// Output tile per block: 16(x) x 16(y) x 8(z) = 2048 outputs, 512 threads,
// 4 z-outputs per thread (processed as two float2-packed z-pairs).
// Staged path (R11, validated): bbox -> LDS via global_load_lds size=4,
// one row-pair (2x32 floats) per instr, pair stride 68 -> ~2-way banks, no
// per-tap swizzle VALU. R12: clamps dropped (bbox margin covers fp error),
// packed v_pk_fma_f32 lerps, mad-form addressing, 16-loads-then-lerps ILP.
// Non-interior / oversized-bbox blocks: proven direct-gather path (R7).
#define TLZ 8
#define SWID 32
#define CAPF 13312             // 52 KB stage (floats) -> 3 blocks/CU

typedef float v2f __attribute__((ext_vector_type(2)));

__device__ __forceinline__ void mm3(const float a[3][3], const float b[3][3], float c[3][3]) {
#pragma unroll
    for (int i = 0; i < 3; ++i)
#pragma unroll
        for (int j = 0; j < 3; ++j)
            c[i][j] = a[i][0]*b[0][j] + a[i][1]*b[1][j] + a[i][2]*b[2][j];
}

__global__ void compose_mats_kernel(const float* __restrict__ affine,
                                    const float* __restrict__ scale,
                                    const float* __restrict__ translate,
                                    const float* __restrict__ shear,
                                    float* __restrict__ mats_out) {
    int b = threadIdx.x;
    if (b >= Bv) return;

    float ax = affine[b*3+0], ay = affine[b*3+1], az = affine[b*3+2];
    float cx = cosf(ax), sx = sinf(ax);
    float cy = cosf(ay), sy = sinf(ay);
    float cz = cosf(az), sz = sinf(az);

    // _mk_mat transposes the written rows -> these are the transposed matrices.
    float rx[3][3] = {{1.f,0.f,0.f},{0.f,cx,sx},{0.f,-sx,cx}};
    float ry[3][3] = {{cy,0.f,-sy},{0.f,1.f,0.f},{sy,0.f,cy}};
    float rz[3][3] = {{cz,sz,0.f},{-sz,cz,0.f},{0.f,0.f,1.f}};

    float t0 = tanf(shear[b*6+0]), t1 = tanf(shear[b*6+1]), t2 = tanf(shear[b*6+2]);
    float t3 = tanf(shear[b*6+3]), t4 = tanf(shear[b*6+4]), t5 = tanf(shear[b*6+5]);
    float sh[3][3] = {{1.f,t2,t4},{t0,1.f,t5},{t1,t3,1.f}};

    float s0 = scale[b*3+0], s1 = scale[b*3+1], s2 = scale[b*3+2];

    float m1[3][3], m2[3][3], m3s[3][3], mat3[3][3];
    mm3(ry, rx, m1);
    mm3(rz, m1, m2);
#pragma unroll
    for (int j = 0; j < 3; ++j) { m3s[0][j] = s0*m2[0][j]; m3s[1][j] = s1*m2[1][j]; m3s[2][j] = s2*m2[2][j]; }
    mm3(sh, m3s, mat3);

    float tr0 = translate[b*3+0], tr1 = translate[b*3+1], tr2 = translate[b*3+2];

    float a00 = mat3[0][0], a01 = mat3[0][1], a02 = mat3[0][2];
    float a10 = mat3[1][0], a11 = mat3[1][1], a12 = mat3[1][2];
    float a20 = mat3[2][0], a21 = mat3[2][1], a22 = mat3[2][2];
    float c00 =  (a11*a22 - a12*a21);
    float c01 = -(a10*a22 - a12*a20);
    float c02 =  (a10*a21 - a11*a20);
    float det = a00*c00 + a01*c01 + a02*c02;
    float rdet = 1.0f / det;
    float inv3[3][3];
    inv3[0][0] = c00*rdet;
    inv3[0][1] = (a02*a21 - a01*a22)*rdet;
    inv3[0][2] = (a01*a12 - a02*a11)*rdet;
    inv3[1][0] = c01*rdet;
    inv3[1][1] = (a00*a22 - a02*a20)*rdet;
    inv3[1][2] = (a02*a10 - a00*a12)*rdet;
    inv3[2][0] = c02*rdet;
    inv3[2][1] = (a01*a20 - a00*a21)*rdet;
    inv3[2][2] = (a00*a11 - a01*a10)*rdet;

    float* mo = mats_out + b*12;
#pragma unroll
    for (int i = 0; i < 3; ++i) {
        mo[i*4+0] = mat3[i][0]; mo[i*4+1] = mat3[i][1]; mo[i*4+2] = mat3[i][2];
    }
    mo[0*4+3] = tr0; mo[1*4+3] = tr1; mo[2*4+3] = tr2;

    float* io = mats_out + 24 + b*12;
#pragma unroll
    for (int i = 0; i < 3; ++i) {
        io[i*4+0] = inv3[i][0]; io[i*4+1] = inv3[i][1]; io[i*4+2] = inv3[i][2];
        io[i*4+3] = -(inv3[i][0]*tr0 + inv3[i][1]*tr1 + inv3[i][2]*tr2);
    }
}

// 8-byte load from a 4-byte-aligned address (single global_load_dwordx2).
__device__ __forceinline__ float2 ld2(const float* p) {
    float2 r;
    __builtin_memcpy(&r, p, 8);
    return r;
}

// Direct global->LDS, 4 bytes/lane: lane l reads its own global addr and
// writes LDS float (base + l). 64 lanes = one 2x32-float row-pair.
__device__ __forceinline__ void gld_lds4(const float* g, float* l) {
    __builtin_amdgcn_global_load_lds(
        (const __attribute__((address_space(1))) unsigned int*)g,
        (__attribute__((address_space(3))) unsigned int*)l, 4, 0, 0);
}

__global__ __launch_bounds__(512) void warp_kernel(const float* __restrict__ src,
                                                   const float* __restrict__ mats,
                                                   float* __restrict__ out) {
    __shared__ float stage[CAPF];   // 52 KB

    int t   = threadIdx.x;
    int lx  = t & 15;
    int ly  = (t >> 4) & 15;
    int lzt = t >> 8;               // 0..1 (4 z-outputs each)

    int W0 = blockIdx.x * 16;
    int H0 = blockIdx.y * 16;
    int zt = blockIdx.z;            // 0 .. (Dv/TLZ)*Bv - 1
    int b  = zt / (Dv/TLZ);         // uniform
    int Z0 = (zt % (Dv/TLZ)) * TLZ;

    const float* M = mats + b*12;   // uniform -> scalar loads
    float m00 = M[0], m01 = M[1],  m02 = M[2],  m03 = M[3];
    float m10 = M[4], m11 = M[5],  m12 = M[6],  m13 = M[7];
    float m20 = M[8], m21 = M[9],  m22 = M[10], m23 = M[11];

    float Cx = 96.0f*(m03 - m00 - m01 - m02) + 95.5f;
    float Cy = 96.0f*(m13 - m10 - m11 - m12) + 95.5f;
    float Cz = 96.0f*(m23 - m20 - m21 - m22) + 95.5f;

    const float* sb = src + (size_t)b * Nv;

    // ---- block-uniform source bbox (tile corners +- half extent) ----
    float bcx = W0 + 8.0f, bcy = H0 + 8.0f, bcz = Z0 + 4.0f;
    float cxv = fmaf(m00, bcx, fmaf(m01, bcy, fmaf(m02, bcz, Cx)));
    float cyv = fmaf(m10, bcx, fmaf(m11, bcy, fmaf(m12, bcz, Cy)));
    float czv = fmaf(m20, bcx, fmaf(m21, bcy, fmaf(m22, bcz, Cz)));
    float hxv = 7.5f*fabsf(m00) + 7.5f*fabsf(m01) + 3.5f*fabsf(m02);
    float hyv = 7.5f*fabsf(m10) + 7.5f*fabsf(m11) + 3.5f*fabsf(m12);
    float hzv = 7.5f*fabsf(m20) + 7.5f*fabsf(m21) + 3.5f*fabsf(m22);

    int bx0 = ((int)floorf(cxv - hxv) - 1) & ~3;
    int by0 = (int)floorf(cyv - hyv) - 1;
    int bz0 = (int)floorf(czv - hzv) - 1;
    int xmax = (int)floorf(cxv + hxv) + 2;         // last tap x
    int ey  = (int)floorf(cyv + hyv) + 3 - by0;
    int ez  = (int)floorf(czv + hzv) + 3 - bz0;

    int nP  = (ey + 1) >> 1;        // row-pairs per plane
    int PST = 68*nP + 4;            // plane stride (floats); +4 shifts banks/plane

    bool interior = (PST*ez <= CAPF) && (xmax - bx0 + 1 <= SWID) &&
                    (bx0 >= 0) && (bx0 + SWID   <= Wv) &&
                    (by0 >= 0) && (by0 + 2*nP   <= Hv) &&
                    (bz0 >= 0) && (bz0 + ez     <= Dv);

    int w = W0 + lx, h = H0 + ly;
    float fw = w + 0.5f, fh = h + 0.5f;
    float fz0 = Z0 + lzt*4 + 0.5f;

    float accs[4];

    if (interior) {
        // ---- phase 1: stage bbox via row-pair DMA (issue first) ----
        int lane = t & 63;
        int wvu  = __builtin_amdgcn_readfirstlane(t >> 6);  // 0..7
        int lrow = lane >> 5;          // row within pair
        int col  = lane & 31;
        int srcb = (bz0*Hv + by0)*Wv + bx0 + lrow*Wv + col;   // per-lane
        for (int dz = wvu; dz < ez; dz += 8) {
            int sp = srcb + dz*(Hv*Wv);     // uniform dz -> s_mul + v_add
            int lb = dz*PST;                // wave-uniform
            for (int j = 0; j < nP; ++j) {
                gld_lds4(sb + sp, &stage[lb + j*68]);
                sp += 2*Wv;
            }
        }

        // ---- per-thread coords (overlaps DMA) ----
        float ixb = fmaf(m00, fw, fmaf(m01, fh, fmaf(m02, fz0, Cx)));
        float iyb = fmaf(m10, fw, fmaf(m11, fh, fmaf(m12, fz0, Cy)));
        float izb = fmaf(m20, fw, fmaf(m21, fh, fmaf(m22, fz0, Cz)));

        asm volatile("s_waitcnt vmcnt(0)" ::: "memory");
        __syncthreads();

        // ---- phase 2: taps, two z-outputs packed per float2 lane ----
#pragma unroll
        for (int zp = 0; zp < 2; ++zp) {
            float zA = (float)(2*zp), zB = (float)(2*zp + 1);
            float ixA = fmaf(m02, zA, ixb), ixB = fmaf(m02, zB, ixb);
            float iyA = fmaf(m12, zA, iyb), iyB = fmaf(m12, zB, iyb);
            float izA = fmaf(m22, zA, izb), izB = fmaf(m22, zB, izb);

            float fxA = floorf(ixA), fxB = floorf(ixB);
            float fyA = floorf(iyA), fyB = floorf(iyB);
            float fzA = floorf(izA), fzB = floorf(izB);

            v2f wx2; wx2.x = ixA - fxA; wx2.y = ixB - fxB;
            v2f wy2; wy2.x = iyA - fyA; wy2.y = iyB - fyB;
            v2f wz2; wz2.x = izA - fzA; wz2.y = izB - fzB;

            // no clamps: bbox margin (+-1 cell) >> fp32 divergence (~1e-4)
            int lixA = (int)fxA - bx0, lixB = (int)fxB - bx0;
            int liyA = (int)fyA - by0, liyB = (int)fyB - by0;
            int lizA = (int)fzA - bz0, lizB = (int)fzB - bz0;

            // o00 = liz*PST + 34*liy - 2*(liy&1) + lix ; o01 = o00 + 32 + 4*(liy&1)
            int oddA = liyA & 1, oddB = liyB & 1;
            int o00A = lizA*PST + 34*liyA - (oddA << 1) + lixA;
            int o00B = lizB*PST + 34*liyB - (oddB << 1) + lixB;
            int o01A = o00A + 32 + (oddA << 2);
            int o01B = o00B + 32 + (oddB << 2);
            int o10A = o00A + PST, o10B = o00B + PST;
            int o11A = o01A + PST, o11B = o01B + PST;

            // all 16 loads first (ds_read2 fusion + ILP), then packed lerps
            v2f v000; v000.x = stage[o00A];   v000.y = stage[o00B];
            v2f v001; v001.x = stage[o00A+1]; v001.y = stage[o00B+1];
            v2f v010; v010.x = stage[o01A];   v010.y = stage[o01B];
            v2f v011; v011.x = stage[o01A+1]; v011.y = stage[o01B+1];
            v2f v100; v100.x = stage[o10A];   v100.y = stage[o10B];
            v2f v101; v101.x = stage[o10A+1]; v101.y = stage[o10B+1];
            v2f v110; v110.x = stage[o11A];   v110.y = stage[o11B];
            v2f v111; v111.x = stage[o11A+1]; v111.y = stage[o11B+1];

            v2f c00 = wx2*(v001 - v000) + v000;
            v2f c01 = wx2*(v011 - v010) + v010;
            v2f c10 = wx2*(v101 - v100) + v100;
            v2f c11 = wx2*(v111 - v110) + v110;
            v2f c0  = wy2*(c01 - c00) + c00;
            v2f c1  = wy2*(c11 - c10) + c10;
            v2f r   = wz2*(c1 - c0) + c0;
            accs[2*zp]   = r.x;
            accs[2*zp+1] = r.y;
        }
    } else {
        // ---- fallback: direct gather (block-uniform; R7 path) ----
        float ixb = fmaf(m00, fw, fmaf(m01, fh, fmaf(m02, fz0, Cx)));
        float iyb = fmaf(m10, fw, fmaf(m11, fh, fmaf(m12, fz0, Cy)));
        float izb = fmaf(m20, fw, fmaf(m21, fh, fmaf(m22, fz0, Cz)));
#pragma unroll
        for (int zi = 0; zi < 4; ++zi) {
            float ix = fmaf(m02, (float)zi, ixb);
            float iy = fmaf(m12, (float)zi, iyb);
            float iz = fmaf(m22, (float)zi, izb);
            float flx = floorf(ix), fly = floorf(iy), flz = floorf(iz);
            float wx = ix - flx, wy = iy - fly, wz = iz - flz;
            int x0 = (int)flx, y0 = (int)fly, z0 = (int)flz;

            float a = 0.0f;
            bool all_in = ((unsigned)x0 < (unsigned)(Wv-1)) &
                          ((unsigned)y0 < (unsigned)(Hv-1)) &
                          ((unsigned)z0 < (unsigned)(Dv-1));
            if (all_in) {
                const float* p = sb + ((z0*Hv + y0)*Wv + x0);
                const float* q = p + Hv*Wv;
                float2 v00 = ld2(p);
                float2 v01 = ld2(p + Wv);
                float2 v10 = ld2(q);
                float2 v11 = ld2(q + Wv);
                float c00 = fmaf(wx, v00.y - v00.x, v00.x);
                float c01 = fmaf(wx, v01.y - v01.x, v01.x);
                float c10 = fmaf(wx, v10.y - v10.x, v10.x);
                float c11 = fmaf(wx, v11.y - v11.x, v11.x);
                float c0  = fmaf(wy, c01 - c00, c00);
                float c1  = fmaf(wy, c11 - c10, c10);
                a = fmaf(wz, c1 - c0, c0);
            } else {
                int x1 = x0 + 1, y1 = y0 + 1, z1 = z0 + 1;
                bool all_out = (x1 < 0) | (x0 >= Wv) | (y1 < 0) | (y0 >= Hv) | (z1 < 0) | (z0 >= Dv);
                if (!all_out) {
                    auto gather = [&](int zz, int yy, int xx) -> float {
                        bool valid = ((unsigned)xx < (unsigned)Wv) &
                                     ((unsigned)yy < (unsigned)Hv) &
                                     ((unsigned)zz < (unsigned)Dv);
                        int xi = min(max(xx, 0), Wv-1);
                        int yi = min(max(yy, 0), Hv-1);
                        int zi2 = min(max(zz, 0), Dv-1);
                        float val = sb[(zi2*Hv + yi)*Wv + xi];
                        return valid ? val : 0.0f;
                    };
                    float owx = 1.0f - wx, owy = 1.0f - wy, owz = 1.0f - wz;
                    a  = gather(z0, y0, x0) * (owz*owy*owx);
                    a += gather(z0, y0, x1) * (owz*owy*wx);
                    a += gather(z0, y1, x0) * (owz*wy*owx);
                    a += gather(z0, y1, x1) * (owz*wy*wx);
                    a += gather(z1, y0, x0) * (wz*owy*owx);
                    a += gather(z1, y0, x1) * (wz*owy*wx);
                    a += gather(z1, y1, x0) * (wz*wy*owx);
                    a += gather(z1, y1, x1) * (wz*wy*wx);
                }
            }
            accs[zi] = a;
        }
    }

    // ---- stores: 16-wide x rows -> full 64B lines, naturally coalesced ----
#pragma unroll
    for (int zi = 0; zi < 4; ++zi) {
        int z = Z0 + lzt*4 + zi;
        __builtin_nontemporal_store(accs[zi], &out[((size_t)(b*Dv + z)*Hv + h)*Wv + w]);
    }
}

extern "C" void kernel_launch(void* const* d_in, const int* in_sizes, int n_in,
                              void* d_out, int out_size, void* d_ws, size_t ws_size,
                              hipStream_t stream) {
    const float* src       = (const float*)d_in[0];
    const float* affine    = (const float*)d_in[1];
    const float* scale     = (const float*)d_in[2];
    const float* translate = (const float*)d_in[3];
    const float* shear     = (const float*)d_in[4];

    float* out  = (float*)d_out;
    float* mats = out + NOUT;   // mat (24 floats) then inv_mat (24 floats)

    compose_mats_kernel<<<1, 64, 0, stream>>>(affine, scale, translate, shear, mats);

    dim3 grid(Wv/16, Hv/16, (Dv/TLZ)*Bv);
    warp_kernel<<<grid, 512, 0, stream>>>(src, mats, out);
}

// Round 13
// 50.969 us; speedup vs baseline: 2.2358x; 1.0213x over previous
//
#include <hip/hip_runtime.h>
#include <math.h>

#define Bv 2
#define Dv 192
#define Hv 192
#define Wv 192
#define Nv (Dv*Hv*Wv)          // 7,077,888 voxels per batch
#define NOUT (Bv*Nv)           // 14,155,776 warped elements

// Output tile per block: 16(x) x 16(y) x 8(z) = 2048 outputs, 512 threads,
// 4 z-outputs per thread (two float2-packed z-pairs).
// R13: staging is UNCONDITIONAL into a clamped window (bbox intersect cap,
// z-truncated centered, clamped into volume). Per-LANE exact test decides
// LDS taps vs direct gather, branching at WAVE granularity (__all). No cap
// cliff, no margins (test is exact), boundary tiles stage too.
// Stage layout (R11): row-pairs (2x32 floats) stride 68, plane stride +4 ->
// ~2-way banks, zero per-tap swizzle VALU, ds_read2_b32 fusion.
#define TLZ 8
#define SWID 32
#define CAPF 13312             // 52 KB stage -> 3 blocks/CU

typedef float v2f __attribute__((ext_vector_type(2)));

__device__ __forceinline__ void mm3(const float a[3][3], const float b[3][3], float c[3][3]) {
#pragma unroll
    for (int i = 0; i < 3; ++i)
#pragma unroll
        for (int j = 0; j < 3; ++j)
            c[i][j] = a[i][0]*b[0][j] + a[i][1]*b[1][j] + a[i][2]*b[2][j];
}

__global__ void compose_mats_kernel(const float* __restrict__ affine,
                                    const float* __restrict__ scale,
                                    const float* __restrict__ translate,
                                    const float* __restrict__ shear,
                                    float* __restrict__ mats_out) {
    int b = threadIdx.x;
    if (b >= Bv) return;

    float ax = affine[b*3+0], ay = affine[b*3+1], az = affine[b*3+2];
    float cx = cosf(ax), sx = sinf(ax);
    float cy = cosf(ay), sy = sinf(ay);
    float cz = cosf(az), sz = sinf(az);

    // _mk_mat transposes the written rows -> these are the transposed matrices.
    float rx[3][3] = {{1.f,0.f,0.f},{0.f,cx,sx},{0.f,-sx,cx}};
    float ry[3][3] = {{cy,0.f,-sy},{0.f,1.f,0.f},{sy,0.f,cy}};
    float rz[3][3] = {{cz,sz,0.f},{-sz,cz,0.f},{0.f,0.f,1.f}};

    float t0 = tanf(shear[b*6+0]), t1 = tanf(shear[b*6+1]), t2 = tanf(shear[b*6+2]);
    float t3 = tanf(shear[b*6+3]), t4 = tanf(shear[b*6+4]), t5 = tanf(shear[b*6+5]);
    float sh[3][3] = {{1.f,t2,t4},{t0,1.f,t5},{t1,t3,1.f}};

    float s0 = scale[b*3+0], s1 = scale[b*3+1], s2 = scale[b*3+2];

    float m1[3][3], m2[3][3], m3s[3][3], mat3[3][3];
    mm3(ry, rx, m1);
    mm3(rz, m1, m2);
#pragma unroll
    for (int j = 0; j < 3; ++j) { m3s[0][j] = s0*m2[0][j]; m3s[1][j] = s1*m2[1][j]; m3s[2][j] = s2*m2[2][j]; }
    mm3(sh, m3s, mat3);

    float tr0 = translate[b*3+0], tr1 = translate[b*3+1], tr2 = translate[b*3+2];

    float a00 = mat3[0][0], a01 = mat3[0][1], a02 = mat3[0][2];
    float a10 = mat3[1][0], a11 = mat3[1][1], a12 = mat3[1][2];
    float a20 = mat3[2][0], a21 = mat3[2][1], a22 = mat3[2][2];
    float c00 =  (a11*a22 - a12*a21);
    float c01 = -(a10*a22 - a12*a20);
    float c02 =  (a10*a21 - a11*a20);
    float det = a00*c00 + a01*c01 + a02*c02;
    float rdet = 1.0f / det;
    float inv3[3][3];
    inv3[0][0] = c00*rdet;
    inv3[0][1] = (a02*a21 - a01*a22)*rdet;
    inv3[0][2] = (a01*a12 - a02*a11)*rdet;
    inv3[1][0] = c01*rdet;
    inv3[1][1] = (a00*a22 - a02*a20)*rdet;
    inv3[1][2] = (a02*a10 - a00*a12)*rdet;
    inv3[2][0] = c02*rdet;
    inv3[2][1] = (a01*a20 - a00*a21)*rdet;
    inv3[2][2] = (a00*a11 - a01*a10)*rdet;

    float* mo = mats_out + b*12;
#pragma unroll
    for (int i = 0; i < 3; ++i) {
        mo[i*4+0] = mat3[i][0]; mo[i*4+1] = mat3[i][1]; mo[i*4+2] = mat3[i][2];
    }
    mo[0*4+3] = tr0; mo[1*4+3] = tr1; mo[2*4+3] = tr2;

    float* io = mats_out + 24 + b*12;
#pragma unroll
    for (int i = 0; i < 3; ++i) {
        io[i*4+0] = inv3[i][0]; io[i*4+1] = inv3[i][1]; io[i*4+2] = inv3[i][2];
        io[i*4+3] = -(inv3[i][0]*tr0 + inv3[i][1]*tr1 + inv3[i][2]*tr2);
    }
}

// 8-byte load from a 4-byte-aligned address (single global_load_dwordx2).
__device__ __forceinline__ float2 ld2(const float* p) {
    float2 r;
    __builtin_memcpy(&r, p, 8);
    return r;
}

// Direct global->LDS, 4 bytes/lane: lane l writes LDS float (base + l).
// 64 lanes = one 2x32-float row-pair.
__device__ __forceinline__ void gld_lds4(const float* g, float* l) {
    __builtin_amdgcn_global_load_lds(
        (const __attribute__((address_space(1))) unsigned int*)g,
        (__attribute__((address_space(3))) unsigned int*)l, 4, 0, 0);
}

__global__ __launch_bounds__(512) void warp_kernel(const float* __restrict__ src,
                                                   const float* __restrict__ mats,
                                                   float* __restrict__ out) {
    __shared__ float stage[CAPF];   // 52 KB

    int t   = threadIdx.x;
    int lx  = t & 15;
    int ly  = (t >> 4) & 15;
    int lzt = t >> 8;               // 0..1 (4 z-outputs each)

    int W0 = blockIdx.x * 16;
    int H0 = blockIdx.y * 16;
    int zt = blockIdx.z;            // 0 .. (Dv/TLZ)*Bv - 1
    int b  = zt / (Dv/TLZ);         // uniform
    int Z0 = (zt % (Dv/TLZ)) * TLZ;

    const float* M = mats + b*12;   // uniform -> scalar loads
    float m00 = M[0], m01 = M[1],  m02 = M[2],  m03 = M[3];
    float m10 = M[4], m11 = M[5],  m12 = M[6],  m13 = M[7];
    float m20 = M[8], m21 = M[9],  m22 = M[10], m23 = M[11];

    float Cx = 96.0f*(m03 - m00 - m01 - m02) + 95.5f;
    float Cy = 96.0f*(m13 - m10 - m11 - m12) + 95.5f;
    float Cz = 96.0f*(m23 - m20 - m21 - m22) + 95.5f;

    const float* sb = src + (size_t)b * Nv;

    // ---- exact block-uniform source extents (corner extents of the tile) ----
    float bcx = W0 + 8.0f, bcy = H0 + 8.0f, bcz = Z0 + 4.0f;
    float cxv = fmaf(m00, bcx, fmaf(m01, bcy, fmaf(m02, bcz, Cx)));
    float cyv = fmaf(m10, bcx, fmaf(m11, bcy, fmaf(m12, bcz, Cy)));
    float czv = fmaf(m20, bcx, fmaf(m21, bcy, fmaf(m22, bcz, Cz)));
    float hxv = 7.5f*fabsf(m00) + 7.5f*fabsf(m01) + 3.5f*fabsf(m02);
    float hyv = 7.5f*fabsf(m10) + 7.5f*fabsf(m11) + 3.5f*fabsf(m12);
    float hzv = 7.5f*fabsf(m20) + 7.5f*fabsf(m21) + 3.5f*fabsf(m22);

    int xlo = (int)floorf(cxv - hxv), xhi1 = (int)floorf(cxv + hxv) + 1;
    int ylo = (int)floorf(cyv - hyv), yhi1 = (int)floorf(cyv + hyv) + 1;
    int zlo = (int)floorf(czv - hzv), zhi1 = (int)floorf(czv + hzv) + 1;

    // ---- staged window: bbox clamped into volume, z truncated to cap ----
    int bx0 = min(max(xlo, 0), Wv - SWID);
    int ey_s = min(yhi1 - ylo + 1, 64);            // nP<=32
    int nP  = (ey_s + 1) >> 1;
    int PST = 68*nP + 4;
    int ez_need = zhi1 - zlo + 1;
    int ez_s = min(ez_need, CAPF / PST);
    int by0 = min(max(ylo, 0), Hv - 2*nP);
    int bz0 = min(max(zlo + ((ez_need - ez_s) >> 1), 0), Dv - max(ez_s, 0));

    bool uok = (xhi1 >= 0) & (xlo < Wv) & (yhi1 >= 0) & (ylo < Hv) &
               (zhi1 >= 0) & (zlo < Dv) & (ez_s >= 2) & (ey_s >= 2);
    if (!uok) ez_s = 0;                            // skip DMA, no LDS use

    int w = W0 + lx, h = H0 + ly;
    float fw = w + 0.5f, fh = h + 0.5f;
    float fz0 = Z0 + lzt*4 + 0.5f;

    // ---- phase 1: stage the window (always; trip count 0 if skipped) ----
    int lane = t & 63;
    int wvu  = __builtin_amdgcn_readfirstlane(t >> 6);  // 0..7
    int lrow = lane >> 5;
    int col  = lane & 31;
    int srcb = (bz0*Hv + by0)*Wv + bx0 + lrow*Wv + col;   // per-lane
    for (int dz = wvu; dz < ez_s; dz += 8) {
        int sp = srcb + dz*(Hv*Wv);
        int lb = dz*PST;
        for (int j = 0; j < nP; ++j) {
            gld_lds4(sb + sp, &stage[lb + j*68]);
            sp += 2*Wv;
        }
    }

    // ---- per-thread coords (overlaps DMA) ----
    float ixb = fmaf(m00, fw, fmaf(m01, fh, fmaf(m02, fz0, Cx)));
    float iyb = fmaf(m10, fw, fmaf(m11, fh, fmaf(m12, fz0, Cy)));
    float izb = fmaf(m20, fw, fmaf(m21, fh, fmaf(m22, fz0, Cz)));

    asm volatile("s_waitcnt vmcnt(0)" ::: "memory");
    __syncthreads();

    // per-lane direct sampler (boundary-masked) for non-staged waves
    auto direct_sample = [&](float ix, float iy, float iz) -> float {
        float flx = floorf(ix), fly = floorf(iy), flz = floorf(iz);
        float wx = ix - flx, wy = iy - fly, wz = iz - flz;
        int x0 = (int)flx, y0 = (int)fly, z0 = (int)flz;
        bool all_in = ((unsigned)x0 < (unsigned)(Wv-1)) &
                      ((unsigned)y0 < (unsigned)(Hv-1)) &
                      ((unsigned)z0 < (unsigned)(Dv-1));
        if (all_in) {
            const float* p = sb + ((z0*Hv + y0)*Wv + x0);
            const float* q = p + Hv*Wv;
            float2 v00 = ld2(p);
            float2 v01 = ld2(p + Wv);
            float2 v10 = ld2(q);
            float2 v11 = ld2(q + Wv);
            float c00 = fmaf(wx, v00.y - v00.x, v00.x);
            float c01 = fmaf(wx, v01.y - v01.x, v01.x);
            float c10 = fmaf(wx, v10.y - v10.x, v10.x);
            float c11 = fmaf(wx, v11.y - v11.x, v11.x);
            float c0  = fmaf(wy, c01 - c00, c00);
            float c1  = fmaf(wy, c11 - c10, c10);
            return fmaf(wz, c1 - c0, c0);
        }
        int x1 = x0 + 1, y1 = y0 + 1, z1 = z0 + 1;
        bool all_out = (x1 < 0) | (x0 >= Wv) | (y1 < 0) | (y0 >= Hv) | (z1 < 0) | (z0 >= Dv);
        if (all_out) return 0.0f;
        auto gather = [&](int zz, int yy, int xx) -> float {
            bool valid = ((unsigned)xx < (unsigned)Wv) &
                         ((unsigned)yy < (unsigned)Hv) &
                         ((unsigned)zz < (unsigned)Dv);
            int xi = min(max(xx, 0), Wv-1);
            int yi = min(max(yy, 0), Hv-1);
            int zi = min(max(zz, 0), Dv-1);
            float val = sb[(zi*Hv + yi)*Wv + xi];
            return valid ? val : 0.0f;
        };
        float owx = 1.0f - wx, owy = 1.0f - wy, owz = 1.0f - wz;
        float a;
        a  = gather(z0, y0, x0) * (owz*owy*owx);
        a += gather(z0, y0, x1) * (owz*owy*wx);
        a += gather(z0, y1, x0) * (owz*wy*owx);
        a += gather(z0, y1, x1) * (owz*wy*wx);
        a += gather(z1, y0, x0) * (wz*owy*owx);
        a += gather(z1, y0, x1) * (wz*owy*wx);
        a += gather(z1, y1, x0) * (wz*wy*owx);
        a += gather(z1, y1, x1) * (wz*wy*wx);
        return a;
    };

    float accs[4];

    // ---- phase 2: two z-outputs packed per float2 lane; wave-level branch ----
#pragma unroll
    for (int zp = 0; zp < 2; ++zp) {
        float zA = (float)(2*zp), zB = (float)(2*zp + 1);
        float ixA = fmaf(m02, zA, ixb), ixB = fmaf(m02, zB, ixb);
        float iyA = fmaf(m12, zA, iyb), iyB = fmaf(m12, zB, iyb);
        float izA = fmaf(m22, zA, izb), izB = fmaf(m22, zB, izb);

        float fxA = floorf(ixA), fxB = floorf(ixB);
        float fyA = floorf(iyA), fyB = floorf(iyB);
        float fzA = floorf(izA), fzB = floorf(izB);

        int dxA = (int)fxA - bx0, dxB = (int)fxB - bx0;
        int dyA = (int)fyA - by0, dyB = (int)fyB - by0;
        int dzA = (int)fzA - bz0, dzB = (int)fzB - bz0;

        // exact per-lane staged test (all 8 taps inside window)
        bool okA = ((unsigned)dxA <= (unsigned)(SWID-2)) &
                   ((unsigned)dyA <= (unsigned)(ey_s-2)) &
                   ((unsigned)dzA <= (unsigned)(ez_s-2));
        bool okB = ((unsigned)dxB <= (unsigned)(SWID-2)) &
                   ((unsigned)dyB <= (unsigned)(ey_s-2)) &
                   ((unsigned)dzB <= (unsigned)(ez_s-2));

        if (uok && __all(okA & okB)) {
            v2f wx2; wx2.x = ixA - fxA; wx2.y = ixB - fxB;
            v2f wy2; wy2.x = iyA - fyA; wy2.y = iyB - fyB;
            v2f wz2; wz2.x = izA - fzA; wz2.y = izB - fzB;

            int oddA = dyA & 1, oddB = dyB & 1;
            int o00A = dzA*PST + 34*dyA - (oddA << 1) + dxA;
            int o00B = dzB*PST + 34*dyB - (oddB << 1) + dxB;
            int o01A = o00A + 32 + (oddA << 2);
            int o01B = o00B + 32 + (oddB << 2);
            int o10A = o00A + PST, o10B = o00B + PST;
            int o11A = o01A + PST, o11B = o01B + PST;

            v2f v000; v000.x = stage[o00A];   v000.y = stage[o00B];
            v2f v001; v001.x = stage[o00A+1]; v001.y = stage[o00B+1];
            v2f v010; v010.x = stage[o01A];   v010.y = stage[o01B];
            v2f v011; v011.x = stage[o01A+1]; v011.y = stage[o01B+1];
            v2f v100; v100.x = stage[o10A];   v100.y = stage[o10B];
            v2f v101; v101.x = stage[o10A+1]; v101.y = stage[o10B+1];
            v2f v110; v110.x = stage[o11A];   v110.y = stage[o11B];
            v2f v111; v111.x = stage[o11A+1]; v111.y = stage[o11B+1];

            v2f c00 = wx2*(v001 - v000) + v000;
            v2f c01 = wx2*(v011 - v010) + v010;
            v2f c10 = wx2*(v101 - v100) + v100;
            v2f c11 = wx2*(v111 - v110) + v110;
            v2f c0  = wy2*(c01 - c00) + c00;
            v2f c1  = wy2*(c11 - c10) + c10;
            v2f r   = wz2*(c1 - c0) + c0;
            accs[2*zp]   = r.x;
            accs[2*zp+1] = r.y;
        } else {
            accs[2*zp]   = direct_sample(ixA, iyA, izA);
            accs[2*zp+1] = direct_sample(ixB, iyB, izB);
        }
    }

    // ---- stores: 16-wide x rows -> full 64B lines, naturally coalesced ----
#pragma unroll
    for (int zi = 0; zi < 4; ++zi) {
        int z = Z0 + lzt*4 + zi;
        __builtin_nontemporal_store(accs[zi], &out[((size_t)(b*Dv + z)*Hv + h)*Wv + w]);
    }
}

extern "C" void kernel_launch(void* const* d_in, const int* in_sizes, int n_in,
                              void* d_out, int out_size, void* d_ws, size_t ws_size,
                              hipStream_t stream) {
    const float* src       = (const float*)d_in[0];
    const float* affine    = (const float*)d_in[1];
    const float* scale     = (const float*)d_in[2];
    const float* translate = (const float*)d_in[3];
    const float* shear     = (const float*)d_in[4];

    float* out  = (float*)d_out;
    float* mats = out + NOUT;   // mat (24 floats) then inv_mat (24 floats)

    compose_mats_kernel<<<1, 64, 0, stream>>>(affine, scale, translate, shear, mats);

    dim3 grid(Wv/16, Hv/16, (Dv/TLZ)*Bv);
    warp_kernel<<<grid, 512, 0, stream>>>(src, mats, out);
}